// Round 6
// baseline (481.927 us; speedup 1.0000x reference)
//
#include <hip/hip_runtime.h>
#include <hip/hip_fp16.h>

#define N    8192
#define FIN  256
#define FOUT 128
#define BN   32

typedef _Float16 half8 __attribute__((ext_vector_type(8)));
typedef _Float16 half4v __attribute__((ext_vector_type(4)));
typedef float floatx4 __attribute__((ext_vector_type(4)));

// v_exp_f32 computes 2^x directly; __exp2f is not declared in these headers.
__device__ __forceinline__ float exp2_fast(float x) { return __builtin_amdgcn_exp2f(x); }

// Direct global->LDS DMA, 16 B per lane: LDS dest = wave-uniform base (HW adds
// lane*16); global src is per-lane.
__device__ __forceinline__ void gload_lds16(const void* g, void* l) {
    __builtin_amdgcn_global_load_lds(
        (const __attribute__((address_space(1))) void*)g,
        (__attribute__((address_space(3))) void*)l, 16, 0, 0);
}

// ---------------------------------------------------------------------------
// Prep (R12-proven arrangement): blocks [0,48) build frag-major fp16 W;
// blocks [48,2096) bit-pack adj -> TRANSPOSED adjbT[w][i] (w = j/64), so
// attn's mask reads are contiguous.
// ---------------------------------------------------------------------------
__global__ __launch_bounds__(256)
void prep_kernel(const float* __restrict__ W0,
                 const float* __restrict__ W1,
                 const float* __restrict__ W2,
                 _Float16* __restrict__ Wf,
                 const int* __restrict__ adj,
                 unsigned long long* __restrict__ adjbT)
{
    if (blockIdx.x < 48) {
        int idx  = blockIdx.x * 256 + threadIdx.x;   // 0..12287
        int lane = idx & 63;
        int frag = idx >> 6;
        int w    = frag >> 6;
        int f    = frag & 63;
        int nt   = f >> 3, kc = f & 7;
        int quad = lane >> 4, lo16 = lane & 15;
        const float* Wp = w == 0 ? W0 : (w == 1 ? W1 : W2);
        half8 v;
#pragma unroll
        for (int jj = 0; jj < 8; jj++)
            v[jj] = (_Float16)Wp[(size_t)(kc * 32 + quad * 8 + jj) * FOUT + nt * 16 + lo16];
        *(half8*)&Wf[(size_t)idx * 8] = v;
    } else {
        // 2048 blocks = 8192 waves; tasks = 128 windows x 512 row-groups.
        // Task (w, rg): rows rg*16..+15, cols w*64..+63 -> 16 ballots ->
        // 128 B contiguous write.
        const int gw   = (blockIdx.x - 48) * 4 + (threadIdx.x >> 6);
        const int lane = threadIdx.x & 63;
#pragma unroll 1
        for (int k = 0; k < 8; k++) {
            int t  = gw + k * 8192;
            int w  = t >> 9;
            int rg = t & 511;
            const int* p = adj + (size_t)(rg * 16) * N + w * 64 + lane;
            unsigned long long myw = 0;
#pragma unroll
            for (int i = 0; i < 16; i++) {
                unsigned long long b = __ballot(p[(size_t)i * N] != 0);
                myw = (lane == i) ? b : myw;
            }
            if (lane < 16)
                adjbT[(size_t)w * N + rg * 16 + lane] = myw;
        }
    }
}

// ---------------------------------------------------------------------------
// H = fp16(log2e * inp@W), H2 = fp16(inp@W2), H3T = fp16((inp@W3)^T).
// (R12-proven, unchanged.)
// ---------------------------------------------------------------------------
__global__ __launch_bounds__(256, 2)
void gemm3_kernel(const float* __restrict__ inp,
                  const _Float16* __restrict__ Wf,
                  _Float16* __restrict__ H,
                  _Float16* __restrict__ H2,
                  _Float16* __restrict__ H3T)
{
    const int which = blockIdx.z;
    const int c0    = blockIdx.y * 64;
    const _Float16* Wfw = Wf + (size_t)which * 64 * 64 * 8;
    const int r0 = blockIdx.x * 64;
    const int tid  = threadIdx.x;
    const int wave = tid >> 6;
    const int lane = tid & 63;
    const int lo16 = lane & 15;
    const int quad = lane >> 4;
    const int r = r0 + wave * 16 + lo16;

    half8 a[8];
#pragma unroll
    for (int kc = 0; kc < 8; kc++) {
        const float* p = &inp[(size_t)r * FIN + kc * 32 + quad * 8];
        float4 v0 = *(const float4*)p;
        float4 v1 = *(const float4*)(p + 4);
        a[kc][0] = (_Float16)v0.x; a[kc][1] = (_Float16)v0.y;
        a[kc][2] = (_Float16)v0.z; a[kc][3] = (_Float16)v0.w;
        a[kc][4] = (_Float16)v1.x; a[kc][5] = (_Float16)v1.y;
        a[kc][6] = (_Float16)v1.z; a[kc][7] = (_Float16)v1.w;
    }

    floatx4 acc[4];
#pragma unroll
    for (int i = 0; i < 4; i++) acc[i] = (floatx4){0.f, 0.f, 0.f, 0.f};

#pragma unroll
    for (int kc = 0; kc < 8; kc++)
#pragma unroll
        for (int nt = 0; nt < 4; nt++) {
            int ntg = (c0 >> 4) + nt;
            half8 b = *(const half8*)&Wfw[(((size_t)ntg * 8 + kc) * 64 + lane) * 8];
            acc[nt] = __builtin_amdgcn_mfma_f32_16x16x32_f16(a[kc], b, acc[nt], 0, 0, 0);
        }

    const int arow = wave * 16 + quad * 4;
    if (which < 2) {
        _Float16* outp = which == 0 ? H : H2;
        const float scale = which == 0 ? 1.44269504f : 1.0f;   // log2(e) folded into Q
#pragma unroll
        for (int nt = 0; nt < 4; nt++)
#pragma unroll
            for (int rr = 0; rr < 4; rr++)
                outp[(size_t)(r0 + arow + rr) * FOUT + c0 + nt * 16 + lo16] =
                    (_Float16)(acc[nt][rr] * scale);
    } else {
#pragma unroll
        for (int nt = 0; nt < 4; nt++) {
            half4v v;
#pragma unroll
            for (int rr = 0; rr < 4; rr++) v[rr] = (_Float16)acc[nt][rr];
            *(half4v*)&H3T[(size_t)(c0 + nt * 16 + lo16) * N + r0 + arow] = v;
        }
    }
}

// ---------------------------------------------------------------------------
// Fused repack: blocks [0,512) build Kf (sigma j-permutation baked in),
// blocks [512,1024) build Vf.  (R12-proven, unchanged.)
// ---------------------------------------------------------------------------
__global__ __launch_bounds__(256)
void repackKV_kernel(const _Float16* __restrict__ H2,
                     const _Float16* __restrict__ H3T,
                     _Float16* __restrict__ Kf,
                     _Float16* __restrict__ Vf)
{
    if (blockIdx.x < 512) {
        int idx  = blockIdx.x * 256 + threadIdx.x;
        int lane = idx & 63;
        int frag = idx >> 6;
        int jb = frag >> 4, f = frag & 15;
        int c = f >> 3, ntj = (f >> 2) & 1, kc = f & 3;
        int quad = lane >> 4, lo16 = lane & 15;
        int srcrow = jb * 64 + c * 32 + (lo16 >> 2) * 8 + ntj * 4 + (lo16 & 3);
        half8 v = *(const half8*)&H2[(size_t)srcrow * FOUT + kc * 32 + quad * 8];
        *(half8*)&Kf[(size_t)idx * 8] = v;
    } else {
        int idx  = (blockIdx.x - 512) * 256 + threadIdx.x;
        int lane = idx & 63;
        int frag = idx >> 6;
        int jb = frag >> 4, f = frag & 15, nt = f >> 1, kc = f & 1;
        int quad = lane >> 4, lo16 = lane & 15;
        half8 v = *(const half8*)&H3T[(size_t)(nt * 16 + lo16) * N + jb * 64 + kc * 32 + quad * 8];
        *(half8*)&Vf[(size_t)idx * 8] = v;
    }
}

// ---------------------------------------------------------------------------
// Flash attention, R15: counted-vmcnt software pipeline (T3/T4).
//  - BN=32 tiles, TRIPLE-buffered KV LDS (48 KB): iter t issues DMA for tile
//    t+2, computes tile t, then `s_waitcnt vmcnt(4)` + raw s_barrier — tile
//    t+1's loads (oldest) proven complete, tile t+2's 4 loads stay IN FLIGHT
//    across the barrier. No vmcnt(0) drain in the main loop.
//  - All adj masks for the block cached to LDS in the prologue (16 KB): zero
//    in-loop global register loads, so the vmcnt counting is exact.
//  - setprio(1) around MFMA clusters (2 independent blocks/CU give the
//    scheduler something to arbitrate).
// ---------------------------------------------------------------------------
template<int JS>
__global__ __launch_bounds__(256, 2)
void attn_kernel(const _Float16* __restrict__ Hq,   // [N][128], log2e folded
                 const _Float16* __restrict__ Kf,
                 const _Float16* __restrict__ Vf,
                 const unsigned long long* __restrict__ adjbT, // [N/64][N]
                 float* __restrict__ OpartT,        // [JS][FOUT][N]
                 float* __restrict__ mpart,         // [JS][N]  (log2 domain)
                 float* __restrict__ lpart)         // [JS][N]
{
    __shared__ __align__(16) _Float16 KV[3][8192];   // 48 KB: [buf][4096 K | 4096 V]
    __shared__ unsigned long long ML[16 * 128];      // 16 KB: [window][i-row]

    const int tid  = threadIdx.x;
    const int wave = tid >> 6;
    const int lane = tid & 63;
    const int lo16 = lane & 15;
    const int quad = lane >> 4;
    const int bid  = blockIdx.x;
    const int js   = bid & (JS - 1);      // XCD affinity (JS=8 == #XCDs)
    const int ib   = bid / JS;
    const int ibase = ib * 128;
    const int iw   = ibase + wave * 32;
    const int jbeg = js * (N / JS);
    constexpr int NIT = (N / JS) / BN;    // 32
    const int jb0  = jbeg >> 6;

    // ---- prologue A: mask cache -> LDS (16 windows x 128 block rows) ----
#pragma unroll
    for (int x = 0; x < 8; x++) {
        int idx  = x * 256 + tid;         // 0..2047
        int w    = idx >> 7;
        int r128 = idx & 127;
        ML[idx] = adjbT[(size_t)(jb0 + w) * N + ibase + r128];
    }

    // ---- prologue B: Q fragments ----
    half8 q[2][4];
#pragma unroll
    for (int isub = 0; isub < 2; isub++)
#pragma unroll
        for (int kc = 0; kc < 4; kc++)
            q[isub][kc] = *(const half8*)&Hq[(size_t)(iw + isub * 16 + lo16) * FOUT + kc * 32 + quad * 8];

    floatx4 O[8][2];
#pragma unroll
    for (int nt = 0; nt < 8; nt++)
#pragma unroll
        for (int s = 0; s < 2; s++) O[nt][s] = (floatx4){0.f, 0.f, 0.f, 0.f};
    float m_s[2] = {-1e12f, -1e12f}, l_s[2] = {0.f, 0.f};

    // staging: one 16 KB tile (K: 8 contiguous frags; V: 8 frags stride 2)
    auto STAGE = [&](int buf, int t2) {
        const int jb2 = jb0 + (t2 >> 1), cb2 = t2 & 1;
        const _Float16* gk = Kf + ((size_t)jb2 * 16 + cb2 * 8) * 512;
#pragma unroll
        for (int r = 0; r < 2; r++)
            gload_lds16(gk + (r * 256 + tid) * 8, &KV[buf][(r * 256 + wave * 64) * 8]);
#pragma unroll
        for (int r = 0; r < 2; r++) {
            const int fv = r * 4 + wave;
            gload_lds16(Vf + ((size_t)jb2 * 16 + fv * 2 + cb2) * 512 + lane * 8,
                        &KV[buf][4096 + fv * 512]);
        }
    };

    // ---- prologue C: fill the pipe 2 tiles deep ----
    STAGE(0, 0);
    STAGE(1, 1);
    // tile0's 4 loads + ML loads drained (tile1's 4 stay in flight); ML
    // ds_writes published before the barrier.
    asm volatile("s_waitcnt vmcnt(4) lgkmcnt(0)" ::: "memory");
    __builtin_amdgcn_sched_barrier(0);
    __builtin_amdgcn_s_barrier();
    __builtin_amdgcn_sched_barrier(0);

    int bc = 0;                            // current buffer
    for (int t = 0; t < NIT; t++) {
        const int cbit = t & 1;

        // ---- issue tile t+2's DMA (stays in flight across this iteration)
        if (t + 2 < NIT) {
            int bs = bc + 2; if (bs >= 3) bs -= 3;
            STAGE(bs, t + 2);
        }

        // ---- masks from LDS (lgkm, not vmcnt) ----
        unsigned long long mw0 = ML[(t >> 1) * 128 + wave * 32 + lo16];
        unsigned long long mw1 = ML[(t >> 1) * 128 + wave * 32 + 16 + lo16];

        const _Float16* kb = &KV[bc][0];
        const _Float16* vb = &KV[bc][4096];

        // ---- S^T = K Q^T : j = cbit*32 + 8*quad + 4*ntj + r, i = s*16+lo16
        floatx4 S[2][2];   // [ntj][s]
        __builtin_amdgcn_s_setprio(1);
#pragma unroll
        for (int ntj = 0; ntj < 2; ntj++) {
            S[ntj][0] = (floatx4){0.f, 0.f, 0.f, 0.f};
            S[ntj][1] = (floatx4){0.f, 0.f, 0.f, 0.f};
#pragma unroll
            for (int kc = 0; kc < 4; kc++) {
                half8 kf = *(const half8*)&kb[((ntj * 4 + kc) * 64 + lane) * 8];
                S[ntj][0] = __builtin_amdgcn_mfma_f32_16x16x32_f16(kf, q[0][kc], S[ntj][0], 0, 0, 0);
                S[ntj][1] = __builtin_amdgcn_mfma_f32_16x16x32_f16(kf, q[1][kc], S[ntj][1], 0, 0, 0);
            }
        }
        __builtin_amdgcn_s_setprio(0);

        // ---- online softmax (exp2 domain), in-place lrelu, deferred rescale
        half8 pb[2];
#pragma unroll
        for (int s = 0; s < 2; s++) {
            float mx = -1e12f;
#pragma unroll
            for (int ntj = 0; ntj < 2; ntj++)
#pragma unroll
                for (int rr = 0; rr < 4; rr++) {
                    float e = S[ntj][s][rr];
                    e = fmaxf(e, 0.2f * e);
                    S[ntj][s][rr] = e;
                    mx = fmaxf(mx, e);
                }
            mx = fmaxf(mx, __shfl_xor(mx, 16));
            mx = fmaxf(mx, __shfl_xor(mx, 32));
            if (__any(mx > m_s[s] + 5.75f)) {
                float mn = fmaxf(m_s[s], mx);
                float al = exp2_fast(m_s[s] - mn);
                m_s[s] = mn;
                l_s[s] *= al;
#pragma unroll
                for (int nt = 0; nt < 8; nt++)
#pragma unroll
                    for (int rr = 0; rr < 4; rr++)
                        O[nt][s][rr] *= al;
            }
            unsigned long long mws = (s == 0) ? mw0 : mw1;
            unsigned m8 = (unsigned)(mws >> (cbit * 32 + quad * 8)) & 0xffu;
            float sum = 0.f;
#pragma unroll
            for (int ntj = 0; ntj < 2; ntj++)
#pragma unroll
                for (int rr = 0; rr < 4; rr++) {
                    float e = S[ntj][s][rr] - m_s[s];
                    float p = ((m8 >> (ntj * 4 + rr)) & 1u) ? exp2_fast(e) : 0.f;
                    sum += p;
                    pb[s][ntj * 4 + rr] = (_Float16)p;
                }
            sum += __shfl_xor(sum, 16);
            sum += __shfl_xor(sum, 32);
            l_s[s] += sum;
        }

        // ---- O^T += V^T P^T ----
        __builtin_amdgcn_s_setprio(1);
#pragma unroll
        for (int nt = 0; nt < 8; nt++) {
            half8 vf = *(const half8*)&vb[(nt * 64 + lane) * 8];
            O[nt][0] = __builtin_amdgcn_mfma_f32_16x16x32_f16(vf, pb[0], O[nt][0], 0, 0, 0);
            O[nt][1] = __builtin_amdgcn_mfma_f32_16x16x32_f16(vf, pb[1], O[nt][1], 0, 0, 0);
        }
        __builtin_amdgcn_s_setprio(0);

        // ---- counted wait + raw barrier: tile t+1 proven resident, tile
        //      t+2's 4 loads remain in flight. Drain fully only at the tail.
        if (t + 2 < NIT) asm volatile("s_waitcnt vmcnt(4)" ::: "memory");
        else             asm volatile("s_waitcnt vmcnt(0)" ::: "memory");
        __builtin_amdgcn_sched_barrier(0);
        __builtin_amdgcn_s_barrier();
        __builtin_amdgcn_sched_barrier(0);
        bc = (bc + 1 == 3) ? 0 : bc + 1;
    }

    // epilogue: O^T[f][i] -> OpartT[js][f][i] (unnormalized) + (m,l)
#pragma unroll
    for (int nt = 0; nt < 8; nt++)
#pragma unroll
        for (int s = 0; s < 2; s++)
#pragma unroll
            for (int rr = 0; rr < 4; rr++) {
                int f = nt * 16 + quad * 4 + rr;
                int i = iw + s * 16 + lo16;
                OpartT[((size_t)js * FOUT + f) * N + i] = O[nt][s][rr];
            }
    if (quad == 0) {
#pragma unroll
        for (int s = 0; s < 2; s++) {
            mpart[js * N + iw + s * 16 + lo16] = m_s[s];
            lpart[js * N + iw + s * 16 + lo16] = l_s[s];
        }
    }
}

// ---------------------------------------------------------------------------
// Combine: f-major partials -> normalize -> ELU -> out[i][f]. (Unchanged.)
// ---------------------------------------------------------------------------
template<int JS>
__global__ __launch_bounds__(256)
void combine_kernel(const float* __restrict__ OpartT,
                    const float* __restrict__ mpart,
                    const float* __restrict__ lpart,
                    float* __restrict__ out)
{
    int idx = blockIdx.x * 256 + threadIdx.x;   // 128 f x 2048 i-groups
    int f  = idx >> 11;
    int i4 = (idx & 2047) << 2;

    float4 M = {-3e38f, -3e38f, -3e38f, -3e38f};
    float4 m[JS];
#pragma unroll
    for (int s = 0; s < JS; s++) {
        m[s] = *(const float4*)&mpart[s * N + i4];
        M.x = fmaxf(M.x, m[s].x); M.y = fmaxf(M.y, m[s].y);
        M.z = fmaxf(M.z, m[s].z); M.w = fmaxf(M.w, m[s].w);
    }
    float4 L = {0.f, 0.f, 0.f, 0.f};
    float4 o = {0.f, 0.f, 0.f, 0.f};
#pragma unroll
    for (int s = 0; s < JS; s++) {
        float4 l = *(const float4*)&lpart[s * N + i4];
        float4 w;
        w.x = exp2_fast(m[s].x - M.x); w.y = exp2_fast(m[s].y - M.y);
        w.z = exp2_fast(m[s].z - M.z); w.w = exp2_fast(m[s].w - M.w);
        L.x += l.x * w.x; L.y += l.y * w.y;
        L.z += l.z * w.z; L.w += l.w * w.w;
        float4 v = *(const float4*)&OpartT[((size_t)s * FOUT + f) * N + i4];
        o.x += w.x * v.x; o.y += w.y * v.y;
        o.z += w.z * v.z; o.w += w.w * v.w;
    }
    float r0 = o.x / L.x, r1 = o.y / L.y, r2 = o.z / L.z, r3 = o.w / L.w;
    out[(size_t)(i4 + 0) * FOUT + f] = r0 > 0.f ? r0 : __expf(r0) - 1.f;
    out[(size_t)(i4 + 1) * FOUT + f] = r1 > 0.f ? r1 : __expf(r1) - 1.f;
    out[(size_t)(i4 + 2) * FOUT + f] = r2 > 0.f ? r2 : __expf(r2) - 1.f;
    out[(size_t)(i4 + 3) * FOUT + f] = r3 > 0.f ? r3 : __expf(r3) - 1.f;
}

// ---------------------------------------------------------------------------
extern "C" void kernel_launch(void* const* d_in, const int* in_sizes, int n_in,
                              void* d_out, int out_size, void* d_ws, size_t ws_size,
                              hipStream_t stream) {
    const float* inp = (const float*)d_in[0];
    const int*   adj = (const int*)d_in[1];
    const float* W0  = (const float*)d_in[2];
    const float* W1  = (const float*)d_in[3];
    const float* W2  = (const float*)d_in[4];
    float* out = (float*)d_out;

    constexpr int JS = 8;
    char* ws = (char*)d_ws;
    _Float16* H    = (_Float16*)(ws);                          // 2 MB
    _Float16* H2   = (_Float16*)(ws + (2u << 20));             // 2 MB
    _Float16* H3T  = (_Float16*)(ws + (4u << 20));             // 2 MB
    _Float16* Wf   = (_Float16*)(ws + (6u << 20));             // 192 KB
    _Float16* Kf   = (_Float16*)(ws + (7u << 20));             // 2 MB
    _Float16* Vf   = (_Float16*)(ws + (9u << 20));             // 2 MB
    float* OpartT  = (float*)(ws + (11u << 20));               // 32 MB
    float* mpart   = (float*)(ws + (43u << 20));               // 256 KB
    float* lpart   = (float*)(ws + (43u << 20) + (size_t)JS * N * sizeof(float));
    unsigned long long* adjbT = (unsigned long long*)(ws + (44u << 20)); // 8 MB

    prep_kernel<<<2096, 256, 0, stream>>>(W0, W1, W2, Wf, adj, adjbT);
    gemm3_kernel<<<dim3(N / 64, 2, 3), 256, 0, stream>>>(inp, Wf, H, H2, H3T);
    repackKV_kernel<<<1024, 256, 0, stream>>>(H2, H3T, Kf, Vf);
    attn_kernel<JS><<<(N / 128) * JS, 256, 0, stream>>>(H, Kf, Vf, adjbT, OpartT, mpart, lpart);
    combine_kernel<JS><<<(FOUT * (N / 4)) / 256, 256, 0, stream>>>(OpartT, mpart, lpart, out);
}

// Round 7
// 431.661 us; speedup vs baseline: 1.1164x; 1.1164x over previous
//
#include <hip/hip_runtime.h>
#include <hip/hip_fp16.h>

#define N    8192
#define FIN  256
#define FOUT 128
#define BN   64

typedef _Float16 half8 __attribute__((ext_vector_type(8)));
typedef _Float16 half4v __attribute__((ext_vector_type(4)));
typedef float floatx4 __attribute__((ext_vector_type(4)));

// v_exp_f32 computes 2^x directly; __exp2f is not declared in these headers.
__device__ __forceinline__ float exp2_fast(float x) { return __builtin_amdgcn_exp2f(x); }

// ---------------------------------------------------------------------------
// W-prep: frag-major fp16 W for coalesced MFMA B-loads.
// ---------------------------------------------------------------------------
__global__ __launch_bounds__(256)
void wprep_kernel(const float* __restrict__ W0,
                  const float* __restrict__ W1,
                  const float* __restrict__ W2,
                  _Float16* __restrict__ Wf)
{
    int idx  = blockIdx.x * 256 + threadIdx.x;   // 0..12287
    int lane = idx & 63;
    int frag = idx >> 6;
    int w    = frag >> 6;
    int f    = frag & 63;
    int nt   = f >> 3, kc = f & 7;
    int quad = lane >> 4, lo16 = lane & 15;
    const float* Wp = w == 0 ? W0 : (w == 1 ? W1 : W2);
    half8 v;
#pragma unroll
    for (int jj = 0; jj < 8; jj++)
        v[jj] = (_Float16)Wp[(size_t)(kc * 32 + quad * 8 + jj) * FOUT + nt * 16 + lo16];
    *(half8*)&Wf[(size_t)idx * 8] = v;
}

// ---------------------------------------------------------------------------
// H = fp16(log2e * inp@W)  (log2e folded so attn softmax runs in exp2 domain),
// H2 = fp16(inp@W2), H3T = fp16((inp@W3)^T). Barrier-free. (R9-proven body.)
// ---------------------------------------------------------------------------
__global__ __launch_bounds__(256, 2)
void gemm3_kernel(const float* __restrict__ inp,
                  const _Float16* __restrict__ Wf,
                  _Float16* __restrict__ H,
                  _Float16* __restrict__ H2,
                  _Float16* __restrict__ H3T)
{
    const int which = blockIdx.z;
    const int c0    = blockIdx.y * 64;
    const _Float16* Wfw = Wf + (size_t)which * 64 * 64 * 8;
    const int r0 = blockIdx.x * 64;
    const int tid  = threadIdx.x;
    const int wave = tid >> 6;
    const int lane = tid & 63;
    const int lo16 = lane & 15;
    const int quad = lane >> 4;
    const int r = r0 + wave * 16 + lo16;

    half8 a[8];
#pragma unroll
    for (int kc = 0; kc < 8; kc++) {
        const float* p = &inp[(size_t)r * FIN + kc * 32 + quad * 8];
        float4 v0 = *(const float4*)p;
        float4 v1 = *(const float4*)(p + 4);
        a[kc][0] = (_Float16)v0.x; a[kc][1] = (_Float16)v0.y;
        a[kc][2] = (_Float16)v0.z; a[kc][3] = (_Float16)v0.w;
        a[kc][4] = (_Float16)v1.x; a[kc][5] = (_Float16)v1.y;
        a[kc][6] = (_Float16)v1.z; a[kc][7] = (_Float16)v1.w;
    }

    floatx4 acc[4];
#pragma unroll
    for (int i = 0; i < 4; i++) acc[i] = (floatx4){0.f, 0.f, 0.f, 0.f};

#pragma unroll
    for (int kc = 0; kc < 8; kc++)
#pragma unroll
        for (int nt = 0; nt < 4; nt++) {
            int ntg = (c0 >> 4) + nt;
            half8 b = *(const half8*)&Wfw[(((size_t)ntg * 8 + kc) * 64 + lane) * 8];
            acc[nt] = __builtin_amdgcn_mfma_f32_16x16x32_f16(a[kc], b, acc[nt], 0, 0, 0);
        }

    const int arow = wave * 16 + quad * 4;
    if (which < 2) {
        _Float16* outp = which == 0 ? H : H2;
        const float scale = which == 0 ? 1.44269504f : 1.0f;   // log2(e) folded into Q
#pragma unroll
        for (int nt = 0; nt < 4; nt++)
#pragma unroll
            for (int rr = 0; rr < 4; rr++)
                outp[(size_t)(r0 + arow + rr) * FOUT + c0 + nt * 16 + lo16] =
                    (_Float16)(acc[nt][rr] * scale);
    } else {
#pragma unroll
        for (int nt = 0; nt < 4; nt++) {
            half4v v;
#pragma unroll
            for (int rr = 0; rr < 4; rr++) v[rr] = (_Float16)acc[nt][rr];
            *(half4v*)&H3T[(size_t)(c0 + nt * 16 + lo16) * N + r0 + arow] = v;
        }
    }
}

// ---------------------------------------------------------------------------
// Fused repack: blocks [0,512) build Kf (sigma j-permutation baked in),
// blocks [512,1024) build Vf. (R9-proven, unchanged.)
// ---------------------------------------------------------------------------
__global__ __launch_bounds__(256)
void repackKV_kernel(const _Float16* __restrict__ H2,
                     const _Float16* __restrict__ H3T,
                     _Float16* __restrict__ Kf,
                     _Float16* __restrict__ Vf)
{
    if (blockIdx.x < 512) {
        int idx  = blockIdx.x * 256 + threadIdx.x;
        int lane = idx & 63;
        int frag = idx >> 6;
        int jb = frag >> 4, f = frag & 15;
        int c = f >> 3, ntj = (f >> 2) & 1, kc = f & 3;
        int quad = lane >> 4, lo16 = lane & 15;
        int srcrow = jb * 64 + c * 32 + (lo16 >> 2) * 8 + ntj * 4 + (lo16 & 3);
        half8 v = *(const half8*)&H2[(size_t)srcrow * FOUT + kc * 32 + quad * 8];
        *(half8*)&Kf[(size_t)idx * 8] = v;
    } else {
        int idx  = (blockIdx.x - 512) * 256 + threadIdx.x;
        int lane = idx & 63;
        int frag = idx >> 6;
        int jb = frag >> 4, f = frag & 15, nt = f >> 1, kc = f & 1;
        int quad = lane >> 4, lo16 = lane & 15;
        half8 v = *(const half8*)&H3T[(size_t)(nt * 16 + lo16) * N + jb * 64 + kc * 32 + quad * 8];
        *(half8*)&Vf[(size_t)idx * 8] = v;
    }
}

// ---------------------------------------------------------------------------
// Flash attention, R16 == exact R9 structure (the 428 us best: in-loop adj
// loads balloted one iter late, reg-staged double-buffered KV LDS, 1 barrier
// per iter, BN=64, JS=8) + three validated softmax micro-opts:
// exp2-domain (log2e pre-folded into Hq), threshold-deferred O-rescale,
// in-place LeakyReLU. No structural change.
// ---------------------------------------------------------------------------
template<int JS>
__global__ __launch_bounds__(256, 2)
void attn_kernel(const _Float16* __restrict__ Hq,   // [N][128], log2e folded
                 const _Float16* __restrict__ Kf,   // permuted frag-major
                 const _Float16* __restrict__ Vf,   // frag-major
                 const int* __restrict__ adj,       // [N][N]
                 float* __restrict__ OpartT,        // [JS][FOUT][N]
                 float* __restrict__ mpart,         // [JS][N]  (log2 domain)
                 float* __restrict__ lpart)         // [JS][N]
{
    __shared__ _Float16 KV[2][16384];   // [buf][16 K frags | 16 V frags]

    const int tid  = threadIdx.x;
    const int wave = tid >> 6;
    const int lane = tid & 63;
    const int lo16 = lane & 15;
    const int quad = lane >> 4;
    const int bid  = blockIdx.x;
    const int js   = bid & (JS - 1);      // XCD affinity
    const int ib   = bid / JS;
    const int iw   = ib * 128 + wave * 32;
    const int jbeg = js * (N / JS);
    const int NIT  = (N / JS) / BN;

    // Q as B-operand fragments for 2 i-subtiles
    half8 q[2][4];
#pragma unroll
    for (int isub = 0; isub < 2; isub++)
#pragma unroll
        for (int kc = 0; kc < 4; kc++)
            q[isub][kc] = *(const half8*)&Hq[(size_t)(iw + isub * 16 + lo16) * FOUT + kc * 32 + quad * 8];

    floatx4 O[8][2];
#pragma unroll
    for (int nt = 0; nt < 8; nt++)
#pragma unroll
        for (int s = 0; s < 2; s++) O[nt][s] = (floatx4){0.f, 0.f, 0.f, 0.f};
    float m_s[2] = {-1e12f, -1e12f}, l_s[2] = {0.f, 0.f};

    // prologue: adj window 0 loads (one iteration of slack before ballot)
    int av[32];
    {
        const int* ap = adj + (size_t)iw * N + jbeg + lane;
#pragma unroll
        for (int x = 0; x < 32; x++) av[x] = ap[(size_t)x * N];
    }

    // prologue: stage KV tile 0 into buf 0
    {
        const int jb0 = jbeg >> 6;
        const _Float16* gk = Kf + (size_t)jb0 * 8192;
        const _Float16* gv = Vf + (size_t)jb0 * 8192;
#pragma unroll
        for (int r = 0; r < 4; r++) {
            int off = (r * 256 + tid) * 8;
            *(half8*)&KV[0][off]        = *(const half8*)&gk[off];
            *(half8*)&KV[0][8192 + off] = *(const half8*)&gv[off];
        }
        __syncthreads();
    }

    int cur = 0;
    for (int it = 0; it < NIT; it++) {
        const int j0 = jbeg + it * BN;

        // ---- 1) ballot the adj window loaded one iteration ago ----
        unsigned long long mw0 = 0, mw1 = 0;
#pragma unroll
        for (int x = 0; x < 16; x++) {
            unsigned long long b0 = __ballot(av[x] != 0);
            unsigned long long b1 = __ballot(av[x + 16] != 0);
            bool sel = (lo16 == x);
            mw0 = sel ? b0 : mw0;
            mw1 = sel ? b1 : mw1;
        }
        unsigned long long mw[2] = {mw0, mw1};

        // ---- 2) prefetch next KV tile into regs (FIRST, so the later
        //         ds_write waits vmcnt(32) and adj stays in flight) ----
        half8 st[8];
        if (it + 1 < NIT) {
            const int jbn = (j0 + BN) >> 6;
            const _Float16* gk = Kf + (size_t)jbn * 8192;
            const _Float16* gv = Vf + (size_t)jbn * 8192;
#pragma unroll
            for (int r = 0; r < 4; r++) {
                int off = (r * 256 + tid) * 8;
                st[r]     = *(const half8*)&gk[off];
                st[r + 4] = *(const half8*)&gv[off];
            }
        }

        // ---- 3) issue adj loads for the NEXT window ----
        if (it + 1 < NIT) {
            const int* ap = adj + (size_t)iw * N + (j0 + BN) + lane;
#pragma unroll
            for (int x = 0; x < 32; x++) av[x] = ap[(size_t)x * N];
        }

        const _Float16* kb = &KV[cur][0];
        const _Float16* vb = &KV[cur][8192];

        // ---- 4) S^T = K Q^T : j = c*32 + 8*quad + 4*ntj + r, i = s*16+lo16
        floatx4 S[2][2][2];   // [c][ntj][isub]
#pragma unroll
        for (int c = 0; c < 2; c++)
#pragma unroll
            for (int ntj = 0; ntj < 2; ntj++) {
                S[c][ntj][0] = (floatx4){0.f, 0.f, 0.f, 0.f};
                S[c][ntj][1] = (floatx4){0.f, 0.f, 0.f, 0.f};
#pragma unroll
                for (int kc = 0; kc < 4; kc++) {
                    half8 kf = *(const half8*)&kb[(((c * 2 + ntj) * 4 + kc) * 64 + lane) * 8];
                    S[c][ntj][0] = __builtin_amdgcn_mfma_f32_16x16x32_f16(kf, q[0][kc], S[c][ntj][0], 0, 0, 0);
                    S[c][ntj][1] = __builtin_amdgcn_mfma_f32_16x16x32_f16(kf, q[1][kc], S[c][ntj][1], 0, 0, 0);
                }
            }

        // ---- 5) online softmax (exp2 domain), in-place lrelu, deferred
        //         rescale: skip the O-wide rescale unless max grew > 5.75
        //         (p then bounded by 2^5.75 ~ 54, fine in fp16) ----
        half8 pb[2][2];       // [isub][c], element jj = 4*ntj + r
        float sum[2] = {0.f, 0.f};
#pragma unroll
        for (int s = 0; s < 2; s++) {
            float mx = -1e12f;
#pragma unroll
            for (int c = 0; c < 2; c++)
#pragma unroll
                for (int ntj = 0; ntj < 2; ntj++)
#pragma unroll
                    for (int r = 0; r < 4; r++) {
                        float e = S[c][ntj][s][r];
                        e = fmaxf(e, 0.2f * e);          // lrelu (scale-commutes)
                        S[c][ntj][s][r] = e;             // store post-lrelu
                        mx = fmaxf(mx, e);
                    }
            mx = fmaxf(mx, __shfl_xor(mx, 16));
            mx = fmaxf(mx, __shfl_xor(mx, 32));
            if (__any(mx > m_s[s] + 5.75f)) {
                float mn = fmaxf(m_s[s], mx);
                float al = exp2_fast(m_s[s] - mn);
                m_s[s] = mn;
                l_s[s] *= al;
#pragma unroll
                for (int nt = 0; nt < 8; nt++)
#pragma unroll
                    for (int r = 0; r < 4; r++)
                        O[nt][s][r] *= al;
            }

            unsigned long long mq = mw[s] >> (quad * 8);
            unsigned mh[2] = { (unsigned)mq, (unsigned)(mq >> 32) };
#pragma unroll
            for (int c = 0; c < 2; c++)
#pragma unroll
                for (int ntj = 0; ntj < 2; ntj++)
#pragma unroll
                    for (int r = 0; r < 4; r++) {
                        float e = S[c][ntj][s][r] - m_s[s];
                        bool bit = (mh[c] >> (ntj * 4 + r)) & 1u;
                        float p = bit ? exp2_fast(e) : 0.f;
                        sum[s] += p;
                        pb[s][c][ntj * 4 + r] = (_Float16)p;
                    }
            sum[s] += __shfl_xor(sum[s], 16);
            sum[s] += __shfl_xor(sum[s], 32);
            l_s[s] += sum[s];
        }

        // ---- 6) O^T += V^T P^T ----
#pragma unroll
        for (int c = 0; c < 2; c++)
#pragma unroll
            for (int nt = 0; nt < 8; nt++) {
                half8 vf = *(const half8*)&vb[((nt * 2 + c) * 64 + lane) * 8];
                O[nt][0] = __builtin_amdgcn_mfma_f32_16x16x32_f16(vf, pb[0][c], O[nt][0], 0, 0, 0);
                O[nt][1] = __builtin_amdgcn_mfma_f32_16x16x32_f16(vf, pb[1][c], O[nt][1], 0, 0, 0);
            }

        // ---- 7) commit prefetched KV tile; one barrier per iter ----
        if (it + 1 < NIT) {
            const int nxt = cur ^ 1;
#pragma unroll
            for (int r = 0; r < 4; r++) {
                int off = (r * 256 + tid) * 8;
                *(half8*)&KV[nxt][off]        = st[r];
                *(half8*)&KV[nxt][8192 + off] = st[r + 4];
            }
        }
        __syncthreads();
        cur ^= 1;
    }

    // epilogue: O^T[f][i] -> OpartT[js][f][i] (unnormalized) + (m,l)
#pragma unroll
    for (int nt = 0; nt < 8; nt++)
#pragma unroll
        for (int s = 0; s < 2; s++)
#pragma unroll
            for (int r = 0; r < 4; r++) {
                int f = nt * 16 + quad * 4 + r;
                int i = iw + s * 16 + lo16;
                OpartT[((size_t)js * FOUT + f) * N + i] = O[nt][s][r];
            }
    if (quad == 0) {
#pragma unroll
        for (int s = 0; s < 2; s++) {
            mpart[js * N + iw + s * 16 + lo16] = m_s[s];
            lpart[js * N + iw + s * 16 + lo16] = l_s[s];
        }
    }
}

// ---------------------------------------------------------------------------
// Combine: f-major partials -> normalize -> ELU -> out[i][f].
// m is in log2 domain -> exp2 for the cross-partial weights.
// ---------------------------------------------------------------------------
template<int JS>
__global__ __launch_bounds__(256)
void combine_kernel(const float* __restrict__ OpartT,
                    const float* __restrict__ mpart,
                    const float* __restrict__ lpart,
                    float* __restrict__ out)
{
    int idx = blockIdx.x * 256 + threadIdx.x;   // 128 f x 2048 i-groups
    int f  = idx >> 11;
    int i4 = (idx & 2047) << 2;

    float4 M = {-3e38f, -3e38f, -3e38f, -3e38f};
    float4 m[JS];
#pragma unroll
    for (int s = 0; s < JS; s++) {
        m[s] = *(const float4*)&mpart[s * N + i4];
        M.x = fmaxf(M.x, m[s].x); M.y = fmaxf(M.y, m[s].y);
        M.z = fmaxf(M.z, m[s].z); M.w = fmaxf(M.w, m[s].w);
    }
    float4 L = {0.f, 0.f, 0.f, 0.f};
    float4 o = {0.f, 0.f, 0.f, 0.f};
#pragma unroll
    for (int s = 0; s < JS; s++) {
        float4 l = *(const float4*)&lpart[s * N + i4];
        float4 w;
        w.x = exp2_fast(m[s].x - M.x); w.y = exp2_fast(m[s].y - M.y);
        w.z = exp2_fast(m[s].z - M.z); w.w = exp2_fast(m[s].w - M.w);
        L.x += l.x * w.x; L.y += l.y * w.y;
        L.z += l.z * w.z; L.w += l.w * w.w;
        float4 v = *(const float4*)&OpartT[((size_t)s * FOUT + f) * N + i4];
        o.x += w.x * v.x; o.y += w.y * v.y;
        o.z += w.z * v.z; o.w += w.w * v.w;
    }
    float r0 = o.x / L.x, r1 = o.y / L.y, r2 = o.z / L.z, r3 = o.w / L.w;
    out[(size_t)(i4 + 0) * FOUT + f] = r0 > 0.f ? r0 : __expf(r0) - 1.f;
    out[(size_t)(i4 + 1) * FOUT + f] = r1 > 0.f ? r1 : __expf(r1) - 1.f;
    out[(size_t)(i4 + 2) * FOUT + f] = r2 > 0.f ? r2 : __expf(r2) - 1.f;
    out[(size_t)(i4 + 3) * FOUT + f] = r3 > 0.f ? r3 : __expf(r3) - 1.f;
}

// ---------------------------------------------------------------------------
extern "C" void kernel_launch(void* const* d_in, const int* in_sizes, int n_in,
                              void* d_out, int out_size, void* d_ws, size_t ws_size,
                              hipStream_t stream) {
    const float* inp = (const float*)d_in[0];
    const int*   adj = (const int*)d_in[1];
    const float* W0  = (const float*)d_in[2];
    const float* W1  = (const float*)d_in[3];
    const float* W2  = (const float*)d_in[4];
    float* out = (float*)d_out;

    constexpr int JS = 8;
    char* ws = (char*)d_ws;
    _Float16* H    = (_Float16*)(ws);                          // 2 MB
    _Float16* H2   = (_Float16*)(ws + (2u << 20));             // 2 MB
    _Float16* H3T  = (_Float16*)(ws + (4u << 20));             // 2 MB
    _Float16* Wf   = (_Float16*)(ws + (6u << 20));             // 192 KB
    _Float16* Kf   = (_Float16*)(ws + (7u << 20));             // 2 MB
    _Float16* Vf   = (_Float16*)(ws + (9u << 20));             // 2 MB
    float* OpartT  = (float*)(ws + (11u << 20));               // 32 MB
    float* mpart   = (float*)(ws + (43u << 20));               // 256 KB
    float* lpart   = (float*)(ws + (43u << 20) + (size_t)JS * N * sizeof(float));

    wprep_kernel<<<48, 256, 0, stream>>>(W0, W1, W2, Wf);
    gemm3_kernel<<<dim3(N / 64, 2, 3), 256, 0, stream>>>(inp, Wf, H, H2, H3T);
    repackKV_kernel<<<1024, 256, 0, stream>>>(H2, H3T, Kf, Vf);
    attn_kernel<JS><<<(N / 128) * JS, 256, 0, stream>>>(H, Kf, Vf, adj, OpartT, mpart, lpart);
    combine_kernel<JS><<<(FOUT * (N / 4)) / 256, 256, 0, stream>>>(OpartT, mpart, lpart, out);
}

// Round 8
// 425.252 us; speedup vs baseline: 1.1333x; 1.0151x over previous
//
#include <hip/hip_runtime.h>
#include <hip/hip_fp16.h>

#define N    8192
#define FIN  256
#define FOUT 128
#define BN   64

typedef _Float16 half8 __attribute__((ext_vector_type(8)));
typedef _Float16 half4v __attribute__((ext_vector_type(4)));
typedef float floatx4 __attribute__((ext_vector_type(4)));

// v_exp_f32 computes 2^x directly; __exp2f is not declared in these headers.
__device__ __forceinline__ float exp2_fast(float x) { return __builtin_amdgcn_exp2f(x); }

// Direct global->LDS DMA, 16 B per lane: LDS dest = wave-uniform base (HW adds
// lane*16); global src is per-lane. (R12-proven staging path.)
__device__ __forceinline__ void gload_lds16(const void* g, void* l) {
    __builtin_amdgcn_global_load_lds(
        (const __attribute__((address_space(1))) void*)g,
        (__attribute__((address_space(3))) void*)l, 16, 0, 0);
}

// ---------------------------------------------------------------------------
// W-prep: frag-major fp16 W for coalesced MFMA B-loads.
// ---------------------------------------------------------------------------
__global__ __launch_bounds__(256)
void wprep_kernel(const float* __restrict__ W0,
                  const float* __restrict__ W1,
                  const float* __restrict__ W2,
                  _Float16* __restrict__ Wf)
{
    int idx  = blockIdx.x * 256 + threadIdx.x;   // 0..12287
    int lane = idx & 63;
    int frag = idx >> 6;
    int w    = frag >> 6;
    int f    = frag & 63;
    int nt   = f >> 3, kc = f & 7;
    int quad = lane >> 4, lo16 = lane & 15;
    const float* Wp = w == 0 ? W0 : (w == 1 ? W1 : W2);
    half8 v;
#pragma unroll
    for (int jj = 0; jj < 8; jj++)
        v[jj] = (_Float16)Wp[(size_t)(kc * 32 + quad * 8 + jj) * FOUT + nt * 16 + lo16];
    *(half8*)&Wf[(size_t)idx * 8] = v;
}

// ---------------------------------------------------------------------------
// H = fp16(log2e * inp@W)  (log2e folded so attn softmax runs in exp2 domain),
// H2 = fp16(inp@W2), H3T = fp16((inp@W3)^T). Barrier-free. (Proven body.)
// ---------------------------------------------------------------------------
__global__ __launch_bounds__(256, 2)
void gemm3_kernel(const float* __restrict__ inp,
                  const _Float16* __restrict__ Wf,
                  _Float16* __restrict__ H,
                  _Float16* __restrict__ H2,
                  _Float16* __restrict__ H3T)
{
    const int which = blockIdx.z;
    const int c0    = blockIdx.y * 64;
    const _Float16* Wfw = Wf + (size_t)which * 64 * 64 * 8;
    const int r0 = blockIdx.x * 64;
    const int tid  = threadIdx.x;
    const int wave = tid >> 6;
    const int lane = tid & 63;
    const int lo16 = lane & 15;
    const int quad = lane >> 4;
    const int r = r0 + wave * 16 + lo16;

    half8 a[8];
#pragma unroll
    for (int kc = 0; kc < 8; kc++) {
        const float* p = &inp[(size_t)r * FIN + kc * 32 + quad * 8];
        float4 v0 = *(const float4*)p;
        float4 v1 = *(const float4*)(p + 4);
        a[kc][0] = (_Float16)v0.x; a[kc][1] = (_Float16)v0.y;
        a[kc][2] = (_Float16)v0.z; a[kc][3] = (_Float16)v0.w;
        a[kc][4] = (_Float16)v1.x; a[kc][5] = (_Float16)v1.y;
        a[kc][6] = (_Float16)v1.z; a[kc][7] = (_Float16)v1.w;
    }

    floatx4 acc[4];
#pragma unroll
    for (int i = 0; i < 4; i++) acc[i] = (floatx4){0.f, 0.f, 0.f, 0.f};

#pragma unroll
    for (int kc = 0; kc < 8; kc++)
#pragma unroll
        for (int nt = 0; nt < 4; nt++) {
            int ntg = (c0 >> 4) + nt;
            half8 b = *(const half8*)&Wfw[(((size_t)ntg * 8 + kc) * 64 + lane) * 8];
            acc[nt] = __builtin_amdgcn_mfma_f32_16x16x32_f16(a[kc], b, acc[nt], 0, 0, 0);
        }

    const int arow = wave * 16 + quad * 4;
    if (which < 2) {
        _Float16* outp = which == 0 ? H : H2;
        const float scale = which == 0 ? 1.44269504f : 1.0f;   // log2(e) folded into Q
#pragma unroll
        for (int nt = 0; nt < 4; nt++)
#pragma unroll
            for (int rr = 0; rr < 4; rr++)
                outp[(size_t)(r0 + arow + rr) * FOUT + c0 + nt * 16 + lo16] =
                    (_Float16)(acc[nt][rr] * scale);
    } else {
#pragma unroll
        for (int nt = 0; nt < 4; nt++) {
            half4v v;
#pragma unroll
            for (int rr = 0; rr < 4; rr++) v[rr] = (_Float16)acc[nt][rr];
            *(half4v*)&H3T[(size_t)(c0 + nt * 16 + lo16) * N + r0 + arow] = v;
        }
    }
}

// ---------------------------------------------------------------------------
// Fused repack: blocks [0,512) build Kf (sigma j-permutation baked in),
// blocks [512,1024) build Vf. (Proven, unchanged.)
// ---------------------------------------------------------------------------
__global__ __launch_bounds__(256)
void repackKV_kernel(const _Float16* __restrict__ H2,
                     const _Float16* __restrict__ H3T,
                     _Float16* __restrict__ Kf,
                     _Float16* __restrict__ Vf)
{
    if (blockIdx.x < 512) {
        int idx  = blockIdx.x * 256 + threadIdx.x;
        int lane = idx & 63;
        int frag = idx >> 6;
        int jb = frag >> 4, f = frag & 15;
        int c = f >> 3, ntj = (f >> 2) & 1, kc = f & 3;
        int quad = lane >> 4, lo16 = lane & 15;
        int srcrow = jb * 64 + c * 32 + (lo16 >> 2) * 8 + ntj * 4 + (lo16 & 3);
        half8 v = *(const half8*)&H2[(size_t)srcrow * FOUT + kc * 32 + quad * 8];
        *(half8*)&Kf[(size_t)idx * 8] = v;
    } else {
        int idx  = (blockIdx.x - 512) * 256 + threadIdx.x;
        int lane = idx & 63;
        int frag = idx >> 6;
        int jb = frag >> 4, f = frag & 15, nt = f >> 1, kc = f & 1;
        int quad = lane >> 4, lo16 = lane & 15;
        half8 v = *(const half8*)&H3T[(size_t)(nt * 16 + lo16) * N + jb * 64 + kc * 32 + quad * 8];
        *(half8*)&Vf[(size_t)idx * 8] = v;
    }
}

// ---------------------------------------------------------------------------
// Flash attention, R17: R9/R16 structure (BN=64, JS=8, 1 barrier/iter) with
// the in-loop machinery stripped to what R12 proved fast:
//  - adj masks: DIRECT per-lane int4 loads (8 x dwordx4/iter, 2 row bases +
//    imm offsets) double-buffered avA/avB. Each lane loads exactly the 32
//    adj values its S fragments need; mask test = (av[r] != 0). Zero ballots,
//    zero cross-lane mask redistribution. Same 268 MB total adj bytes.
//  - KV staging: global_load_lds DMA (no VGPR round-trip, no ds_writes),
//    double-buffered; the per-iter __syncthreads drains it.
// Even/odd unrolled iteration pair keeps all av/buffer indexing static.
// ---------------------------------------------------------------------------
template<int JS>
__global__ __launch_bounds__(256, 2)
void attn_kernel(const _Float16* __restrict__ Hq,   // [N][128], log2e folded
                 const _Float16* __restrict__ Kf,   // permuted frag-major
                 const _Float16* __restrict__ Vf,   // frag-major
                 const int* __restrict__ adj,       // [N][N]
                 float* __restrict__ OpartT,        // [JS][FOUT][N]
                 float* __restrict__ mpart,         // [JS][N]  (log2 domain)
                 float* __restrict__ lpart)         // [JS][N]
{
    __shared__ __align__(16) _Float16 KV[2][16384];   // [buf][16 K frags | 16 V frags]

    const int tid  = threadIdx.x;
    const int wave = tid >> 6;
    const int lane = tid & 63;
    const int lo16 = lane & 15;
    const int quad = lane >> 4;
    const int bid  = blockIdx.x;
    const int js   = bid & (JS - 1);      // XCD affinity
    const int ib   = bid / JS;
    const int iw   = ib * 128 + wave * 32;
    const int jbeg = js * (N / JS);
    const int NIT  = (N / JS) / BN;       // 16 (even)
    const int jb0  = jbeg >> 6;

    // Q as B-operand fragments for 2 i-subtiles
    half8 q[2][4];
#pragma unroll
    for (int isub = 0; isub < 2; isub++)
#pragma unroll
        for (int kc = 0; kc < 4; kc++)
            q[isub][kc] = *(const half8*)&Hq[(size_t)(iw + isub * 16 + lo16) * FOUT + kc * 32 + quad * 8];

    floatx4 O[8][2];
#pragma unroll
    for (int nt = 0; nt < 8; nt++)
#pragma unroll
        for (int s = 0; s < 2; s++) O[nt][s] = (floatx4){0.f, 0.f, 0.f, 0.f};
    float m_s[2] = {-1e12f, -1e12f}, l_s[2] = {0.f, 0.f};

    // per-lane adj row bases (row s=0 and s=1), advanced by BN each iter
    const int* abase0 = adj + (size_t)(iw + lo16) * N + jbeg + quad * 8;
    const int* abase1 = abase0 + (size_t)16 * N;

    // adj value regs: av[s*4 + c*2 + ntj][r] = adj[i][j0 + c*32+ntj*4 + r]
    int4 avA[8], avB[8];

    auto LOADAV = [&](int4 (&av)[8], int it) {
        const int* b0 = abase0 + it * BN;
        const int* b1 = abase1 + it * BN;
        av[0] = *(const int4*)(b0 + 0);
        av[1] = *(const int4*)(b0 + 4);
        av[2] = *(const int4*)(b0 + 32);
        av[3] = *(const int4*)(b0 + 36);
        av[4] = *(const int4*)(b1 + 0);
        av[5] = *(const int4*)(b1 + 4);
        av[6] = *(const int4*)(b1 + 32);
        av[7] = *(const int4*)(b1 + 36);
    };

    auto STAGE = [&](int nxt, int jbn) {
        const _Float16* gk = Kf + (size_t)jbn * 8192;
        const _Float16* gv = Vf + (size_t)jbn * 8192;
#pragma unroll
        for (int r = 0; r < 4; r++) {
            int goff = (r * 256 + tid) * 8;
            int loff = (r * 256 + wave * 64) * 8;           // wave-uniform base
            gload_lds16(gk + goff, &KV[nxt][loff]);
            gload_lds16(gv + goff, &KV[nxt][8192 + loff]);
        }
    };

    // prologue: stage tile 0, load adj window 0
    STAGE(0, jb0);
    LOADAV(avA, 0);
    __syncthreads();   // drains vmcnt(0): tile 0 + window 0 resident

    auto ITER = [&](int it, int4 (&avc)[8], int4 (&avn)[8], int cur) {
        // ---- 1) issue next tile's DMA + next adj window (full iter of slack)
        if (it + 1 < NIT) {
            STAGE(cur ^ 1, jb0 + it + 1);
            LOADAV(avn, it + 1);
        }

        const _Float16* kb = &KV[cur][0];
        const _Float16* vb = &KV[cur][8192];

        // ---- 2) S^T = K Q^T : j = c*32 + 8*quad + 4*ntj + r, i = s*16+lo16
        floatx4 S[2][2][2];   // [c][ntj][isub]
#pragma unroll
        for (int c = 0; c < 2; c++)
#pragma unroll
            for (int ntj = 0; ntj < 2; ntj++) {
                S[c][ntj][0] = (floatx4){0.f, 0.f, 0.f, 0.f};
                S[c][ntj][1] = (floatx4){0.f, 0.f, 0.f, 0.f};
#pragma unroll
                for (int kc = 0; kc < 4; kc++) {
                    half8 kf = *(const half8*)&kb[(((c * 2 + ntj) * 4 + kc) * 64 + lane) * 8];
                    S[c][ntj][0] = __builtin_amdgcn_mfma_f32_16x16x32_f16(kf, q[0][kc], S[c][ntj][0], 0, 0, 0);
                    S[c][ntj][1] = __builtin_amdgcn_mfma_f32_16x16x32_f16(kf, q[1][kc], S[c][ntj][1], 0, 0, 0);
                }
            }

        // ---- 3) online softmax (exp2 domain), in-place lrelu, deferred
        //         rescale, DIRECT adj mask test (no ballots) ----
        half8 pb[2][2];       // [isub][c], element jj = 4*ntj + r
#pragma unroll
        for (int s = 0; s < 2; s++) {
            float mx = -1e12f;
#pragma unroll
            for (int c = 0; c < 2; c++)
#pragma unroll
                for (int ntj = 0; ntj < 2; ntj++)
#pragma unroll
                    for (int r = 0; r < 4; r++) {
                        float e = S[c][ntj][s][r];
                        e = fmaxf(e, 0.2f * e);          // lrelu (scale-commutes)
                        S[c][ntj][s][r] = e;             // store post-lrelu
                        mx = fmaxf(mx, e);
                    }
            mx = fmaxf(mx, __shfl_xor(mx, 16));
            mx = fmaxf(mx, __shfl_xor(mx, 32));
            if (__any(mx > m_s[s] + 5.75f)) {
                float mn = fmaxf(m_s[s], mx);
                float al = exp2_fast(m_s[s] - mn);
                m_s[s] = mn;
                l_s[s] *= al;
#pragma unroll
                for (int nt = 0; nt < 8; nt++)
#pragma unroll
                    for (int r = 0; r < 4; r++)
                        O[nt][s][r] *= al;
            }

            float sum = 0.f;
#pragma unroll
            for (int c = 0; c < 2; c++)
#pragma unroll
                for (int ntj = 0; ntj < 2; ntj++) {
                    int4 av = avc[s * 4 + c * 2 + ntj];
#pragma unroll
                    for (int r = 0; r < 4; r++) {
                        float e = S[c][ntj][s][r] - m_s[s];
                        int a = (r == 0) ? av.x : (r == 1) ? av.y : (r == 2) ? av.z : av.w;
                        float p = (a != 0) ? exp2_fast(e) : 0.f;
                        sum += p;
                        pb[s][c][ntj * 4 + r] = (_Float16)p;
                    }
                }
            sum += __shfl_xor(sum, 16);
            sum += __shfl_xor(sum, 32);
            l_s[s] += sum;
        }

        // ---- 4) O^T += V^T P^T ----
#pragma unroll
        for (int c = 0; c < 2; c++)
#pragma unroll
            for (int nt = 0; nt < 8; nt++) {
                half8 vf = *(const half8*)&vb[((nt * 2 + c) * 64 + lane) * 8];
                O[nt][0] = __builtin_amdgcn_mfma_f32_16x16x32_f16(vf, pb[0][c], O[nt][0], 0, 0, 0);
                O[nt][1] = __builtin_amdgcn_mfma_f32_16x16x32_f16(vf, pb[1][c], O[nt][1], 0, 0, 0);
            }

        // ---- 5) single barrier: drains this iter's DMA + adj loads ----
        __syncthreads();
    };

    for (int it2 = 0; it2 < NIT; it2 += 2) {
        ITER(it2,     avA, avB, 0);
        ITER(it2 + 1, avB, avA, 1);
    }

    // epilogue: O^T[f][i] -> OpartT[js][f][i] (unnormalized) + (m,l)
#pragma unroll
    for (int nt = 0; nt < 8; nt++)
#pragma unroll
        for (int s = 0; s < 2; s++)
#pragma unroll
            for (int r = 0; r < 4; r++) {
                int f = nt * 16 + quad * 4 + r;
                int i = iw + s * 16 + lo16;
                OpartT[((size_t)js * FOUT + f) * N + i] = O[nt][s][r];
            }
    if (quad == 0) {
#pragma unroll
        for (int s = 0; s < 2; s++) {
            mpart[js * N + iw + s * 16 + lo16] = m_s[s];
            lpart[js * N + iw + s * 16 + lo16] = l_s[s];
        }
    }
}

// ---------------------------------------------------------------------------
// Combine: f-major partials -> normalize -> ELU -> out[i][f].
// m is in log2 domain -> exp2 for the cross-partial weights.
// ---------------------------------------------------------------------------
template<int JS>
__global__ __launch_bounds__(256)
void combine_kernel(const float* __restrict__ OpartT,
                    const float* __restrict__ mpart,
                    const float* __restrict__ lpart,
                    float* __restrict__ out)
{
    int idx = blockIdx.x * 256 + threadIdx.x;   // 128 f x 2048 i-groups
    int f  = idx >> 11;
    int i4 = (idx & 2047) << 2;

    float4 M = {-3e38f, -3e38f, -3e38f, -3e38f};
    float4 m[JS];
#pragma unroll
    for (int s = 0; s < JS; s++) {
        m[s] = *(const float4*)&mpart[s * N + i4];
        M.x = fmaxf(M.x, m[s].x); M.y = fmaxf(M.y, m[s].y);
        M.z = fmaxf(M.z, m[s].z); M.w = fmaxf(M.w, m[s].w);
    }
    float4 L = {0.f, 0.f, 0.f, 0.f};
    float4 o = {0.f, 0.f, 0.f, 0.f};
#pragma unroll
    for (int s = 0; s < JS; s++) {
        float4 l = *(const float4*)&lpart[s * N + i4];
        float4 w;
        w.x = exp2_fast(m[s].x - M.x); w.y = exp2_fast(m[s].y - M.y);
        w.z = exp2_fast(m[s].z - M.z); w.w = exp2_fast(m[s].w - M.w);
        L.x += l.x * w.x; L.y += l.y * w.y;
        L.z += l.z * w.z; L.w += l.w * w.w;
        float4 v = *(const float4*)&OpartT[((size_t)s * FOUT + f) * N + i4];
        o.x += w.x * v.x; o.y += w.y * v.y;
        o.z += w.z * v.z; o.w += w.w * v.w;
    }
    float r0 = o.x / L.x, r1 = o.y / L.y, r2 = o.z / L.z, r3 = o.w / L.w;
    out[(size_t)(i4 + 0) * FOUT + f] = r0 > 0.f ? r0 : __expf(r0) - 1.f;
    out[(size_t)(i4 + 1) * FOUT + f] = r1 > 0.f ? r1 : __expf(r1) - 1.f;
    out[(size_t)(i4 + 2) * FOUT + f] = r2 > 0.f ? r2 : __expf(r2) - 1.f;
    out[(size_t)(i4 + 3) * FOUT + f] = r3 > 0.f ? r3 : __expf(r3) - 1.f;
}

// ---------------------------------------------------------------------------
extern "C" void kernel_launch(void* const* d_in, const int* in_sizes, int n_in,
                              void* d_out, int out_size, void* d_ws, size_t ws_size,
                              hipStream_t stream) {
    const float* inp = (const float*)d_in[0];
    const int*   adj = (const int*)d_in[1];
    const float* W0  = (const float*)d_in[2];
    const float* W1  = (const float*)d_in[3];
    const float* W2  = (const float*)d_in[4];
    float* out = (float*)d_out;

    constexpr int JS = 8;
    char* ws = (char*)d_ws;
    _Float16* H    = (_Float16*)(ws);                          // 2 MB
    _Float16* H2   = (_Float16*)(ws + (2u << 20));             // 2 MB
    _Float16* H3T  = (_Float16*)(ws + (4u << 20));             // 2 MB
    _Float16* Wf   = (_Float16*)(ws + (6u << 20));             // 192 KB
    _Float16* Kf   = (_Float16*)(ws + (7u << 20));             // 2 MB
    _Float16* Vf   = (_Float16*)(ws + (9u << 20));             // 2 MB
    float* OpartT  = (float*)(ws + (11u << 20));               // 32 MB
    float* mpart   = (float*)(ws + (43u << 20));               // 256 KB
    float* lpart   = (float*)(ws + (43u << 20) + (size_t)JS * N * sizeof(float));

    wprep_kernel<<<48, 256, 0, stream>>>(W0, W1, W2, Wf);
    gemm3_kernel<<<dim3(N / 64, 2, 3), 256, 0, stream>>>(inp, Wf, H, H2, H3T);
    repackKV_kernel<<<1024, 256, 0, stream>>>(H2, H3T, Kf, Vf);
    attn_kernel<JS><<<(N / 128) * JS, 256, 0, stream>>>(H, Kf, Vf, adj, OpartT, mpart, lpart);
    combine_kernel<JS><<<(FOUT * (N / 4)) / 256, 256, 0, stream>>>(OpartT, mpart, lpart, out);
}

// Round 9
// 423.514 us; speedup vs baseline: 1.1379x; 1.0041x over previous
//
#include <hip/hip_runtime.h>
#include <hip/hip_fp16.h>

#define N    8192
#define FIN  256
#define FOUT 128
#define BN   64

typedef _Float16 half8 __attribute__((ext_vector_type(8)));
typedef _Float16 half4v __attribute__((ext_vector_type(4)));
typedef float floatx4 __attribute__((ext_vector_type(4)));

// v_exp_f32 computes 2^x directly; __exp2f is not declared in these headers.
__device__ __forceinline__ float exp2_fast(float x) { return __builtin_amdgcn_exp2f(x); }

// Direct global->LDS DMA, 16 B per lane: LDS dest = wave-uniform base (HW adds
// lane*16); global src is per-lane.
__device__ __forceinline__ void gload_lds16(const void* g, void* l) {
    __builtin_amdgcn_global_load_lds(
        (const __attribute__((address_space(1))) void*)g,
        (__attribute__((address_space(3))) void*)l, 16, 0, 0);
}

// ---------------------------------------------------------------------------
// W-prep: frag-major fp16 W for coalesced MFMA B-loads.
// ---------------------------------------------------------------------------
__global__ __launch_bounds__(256)
void wprep_kernel(const float* __restrict__ W0,
                  const float* __restrict__ W1,
                  const float* __restrict__ W2,
                  _Float16* __restrict__ Wf)
{
    int idx  = blockIdx.x * 256 + threadIdx.x;   // 0..12287
    int lane = idx & 63;
    int frag = idx >> 6;
    int w    = frag >> 6;
    int f    = frag & 63;
    int nt   = f >> 3, kc = f & 7;
    int quad = lane >> 4, lo16 = lane & 15;
    const float* Wp = w == 0 ? W0 : (w == 1 ? W1 : W2);
    half8 v;
#pragma unroll
    for (int jj = 0; jj < 8; jj++)
        v[jj] = (_Float16)Wp[(size_t)(kc * 32 + quad * 8 + jj) * FOUT + nt * 16 + lo16];
    *(half8*)&Wf[(size_t)idx * 8] = v;
}

// ---------------------------------------------------------------------------
// H = fp16(log2e * inp@W), H2 = fp16(inp@W2), H3T = fp16((inp@W3)^T).
// (Proven body, unchanged.)
// ---------------------------------------------------------------------------
__global__ __launch_bounds__(256, 2)
void gemm3_kernel(const float* __restrict__ inp,
                  const _Float16* __restrict__ Wf,
                  _Float16* __restrict__ H,
                  _Float16* __restrict__ H2,
                  _Float16* __restrict__ H3T)
{
    const int which = blockIdx.z;
    const int c0    = blockIdx.y * 64;
    const _Float16* Wfw = Wf + (size_t)which * 64 * 64 * 8;
    const int r0 = blockIdx.x * 64;
    const int tid  = threadIdx.x;
    const int wave = tid >> 6;
    const int lane = tid & 63;
    const int lo16 = lane & 15;
    const int quad = lane >> 4;
    const int r = r0 + wave * 16 + lo16;

    half8 a[8];
#pragma unroll
    for (int kc = 0; kc < 8; kc++) {
        const float* p = &inp[(size_t)r * FIN + kc * 32 + quad * 8];
        float4 v0 = *(const float4*)p;
        float4 v1 = *(const float4*)(p + 4);
        a[kc][0] = (_Float16)v0.x; a[kc][1] = (_Float16)v0.y;
        a[kc][2] = (_Float16)v0.z; a[kc][3] = (_Float16)v0.w;
        a[kc][4] = (_Float16)v1.x; a[kc][5] = (_Float16)v1.y;
        a[kc][6] = (_Float16)v1.z; a[kc][7] = (_Float16)v1.w;
    }

    floatx4 acc[4];
#pragma unroll
    for (int i = 0; i < 4; i++) acc[i] = (floatx4){0.f, 0.f, 0.f, 0.f};

#pragma unroll
    for (int kc = 0; kc < 8; kc++)
#pragma unroll
        for (int nt = 0; nt < 4; nt++) {
            int ntg = (c0 >> 4) + nt;
            half8 b = *(const half8*)&Wfw[(((size_t)ntg * 8 + kc) * 64 + lane) * 8];
            acc[nt] = __builtin_amdgcn_mfma_f32_16x16x32_f16(a[kc], b, acc[nt], 0, 0, 0);
        }

    const int arow = wave * 16 + quad * 4;
    if (which < 2) {
        _Float16* outp = which == 0 ? H : H2;
        const float scale = which == 0 ? 1.44269504f : 1.0f;   // log2(e) folded into Q
#pragma unroll
        for (int nt = 0; nt < 4; nt++)
#pragma unroll
            for (int rr = 0; rr < 4; rr++)
                outp[(size_t)(r0 + arow + rr) * FOUT + c0 + nt * 16 + lo16] =
                    (_Float16)(acc[nt][rr] * scale);
    } else {
#pragma unroll
        for (int nt = 0; nt < 4; nt++) {
            half4v v;
#pragma unroll
            for (int rr = 0; rr < 4; rr++) v[rr] = (_Float16)acc[nt][rr];
            *(half4v*)&H3T[(size_t)(c0 + nt * 16 + lo16) * N + r0 + arow] = v;
        }
    }
}

// ---------------------------------------------------------------------------
// Fused repack: blocks [0,512) build Kf (sigma j-permutation baked in),
// blocks [512,1024) build Vf. (Proven, unchanged.)
// ---------------------------------------------------------------------------
__global__ __launch_bounds__(256)
void repackKV_kernel(const _Float16* __restrict__ H2,
                     const _Float16* __restrict__ H3T,
                     _Float16* __restrict__ Kf,
                     _Float16* __restrict__ Vf)
{
    if (blockIdx.x < 512) {
        int idx  = blockIdx.x * 256 + threadIdx.x;
        int lane = idx & 63;
        int frag = idx >> 6;
        int jb = frag >> 4, f = frag & 15;
        int c = f >> 3, ntj = (f >> 2) & 1, kc = f & 3;
        int quad = lane >> 4, lo16 = lane & 15;
        int srcrow = jb * 64 + c * 32 + (lo16 >> 2) * 8 + ntj * 4 + (lo16 & 3);
        half8 v = *(const half8*)&H2[(size_t)srcrow * FOUT + kc * 32 + quad * 8];
        *(half8*)&Kf[(size_t)idx * 8] = v;
    } else {
        int idx  = (blockIdx.x - 512) * 256 + threadIdx.x;
        int lane = idx & 63;
        int frag = idx >> 6;
        int jb = frag >> 4, f = frag & 15, nt = f >> 1, kc = f & 1;
        int quad = lane >> 4, lo16 = lane & 15;
        half8 v = *(const half8*)&H3T[(size_t)(nt * 16 + lo16) * N + jb * 64 + kc * 32 + quad * 8];
        *(half8*)&Vf[(size_t)idx * 8] = v;
    }
}

// ---------------------------------------------------------------------------
// Flash attention, R18: 512-thread blocks, 8 waves x 16 i-rows each (was
// 4 waves x 32). Same grid (512 blocks), same 64 KB double-buffered KV via
// global_load_lds, same bytes — but 16 waves/CU = 4 waves/SIMD (2x latency
// hiding) and per-wave serial chain halved. VGPR kept <= 128 (the 4-wave/SIMD
// budget) by packing the prefetched adj window into a u32 bitmask at the top
// of each iter, recycling the 16 prefetch VGPRs.
// ---------------------------------------------------------------------------
template<int JS>
__global__ __launch_bounds__(512, 2)
void attn_kernel(const _Float16* __restrict__ Hq,   // [N][128], log2e folded
                 const _Float16* __restrict__ Kf,   // permuted frag-major
                 const _Float16* __restrict__ Vf,   // frag-major
                 const int* __restrict__ adj,       // [N][N]
                 float* __restrict__ OpartT,        // [JS][FOUT][N]
                 float* __restrict__ mpart,         // [JS][N]  (log2 domain)
                 float* __restrict__ lpart)         // [JS][N]
{
    __shared__ __align__(16) _Float16 KV[2][16384];   // [buf][16 K frags | 16 V frags]

    const int tid  = threadIdx.x;        // 0..511
    const int wave = tid >> 6;           // 0..7
    const int lane = tid & 63;
    const int lo16 = lane & 15;
    const int quad = lane >> 4;
    const int bid  = blockIdx.x;
    const int js   = bid & (JS - 1);     // XCD affinity
    const int ib   = bid / JS;
    const int iw   = ib * 128 + wave * 16;   // this wave's 16-row slice
    const int irow = iw + lo16;              // this lane's i-row
    const int jbeg = js * (N / JS);
    const int NIT  = (N / JS) / BN;      // 16 (even)
    const int jb0  = jbeg >> 6;

    // Q fragments (B-operand) for this lane's row
    half8 q[4];
#pragma unroll
    for (int kc = 0; kc < 4; kc++)
        q[kc] = *(const half8*)&Hq[(size_t)irow * FOUT + kc * 32 + quad * 8];

    floatx4 O[8];
#pragma unroll
    for (int nt = 0; nt < 8; nt++) O[nt] = (floatx4){0.f, 0.f, 0.f, 0.f};
    float m_s = -1e12f, l_s = 0.f;

    // per-lane adj base: row irow, col group quad*8 within each 64-window
    const int* abase = adj + (size_t)irow * N + jbeg + quad * 8;

    int4 pv[4];   // prefetched adj values: pv[c*2+ntj].{x,y,z,w} = j r=0..3
    auto LOADAV = [&](int it) {
        const int* b = abase + it * BN;
        pv[0] = *(const int4*)(b + 0);
        pv[1] = *(const int4*)(b + 4);
        pv[2] = *(const int4*)(b + 32);
        pv[3] = *(const int4*)(b + 36);
    };
    // pack pv -> u32 mask, bit (c*8 + ntj*4 + r); frees pv for next prefetch
    auto PACK = [&]() -> unsigned {
        unsigned m = 0;
        m |= (pv[0].x != 0) ? 1u << 0  : 0u;  m |= (pv[0].y != 0) ? 1u << 1  : 0u;
        m |= (pv[0].z != 0) ? 1u << 2  : 0u;  m |= (pv[0].w != 0) ? 1u << 3  : 0u;
        m |= (pv[1].x != 0) ? 1u << 4  : 0u;  m |= (pv[1].y != 0) ? 1u << 5  : 0u;
        m |= (pv[1].z != 0) ? 1u << 6  : 0u;  m |= (pv[1].w != 0) ? 1u << 7  : 0u;
        m |= (pv[2].x != 0) ? 1u << 8  : 0u;  m |= (pv[2].y != 0) ? 1u << 9  : 0u;
        m |= (pv[2].z != 0) ? 1u << 10 : 0u;  m |= (pv[2].w != 0) ? 1u << 11 : 0u;
        m |= (pv[3].x != 0) ? 1u << 12 : 0u;  m |= (pv[3].y != 0) ? 1u << 13 : 0u;
        m |= (pv[3].z != 0) ? 1u << 14 : 0u;  m |= (pv[3].w != 0) ? 1u << 15 : 0u;
        return m;
    };

    auto STAGE = [&](int nxt, int jbn) {
        const _Float16* gk = Kf + (size_t)jbn * 8192;
        const _Float16* gv = Vf + (size_t)jbn * 8192;
#pragma unroll
        for (int r = 0; r < 2; r++) {
            int goff = (r * 512 + tid) * 8;
            int loff = (r * 512 + wave * 64) * 8;            // wave-uniform base
            gload_lds16(gk + goff, &KV[nxt][loff]);
            gload_lds16(gv + goff, &KV[nxt][8192 + loff]);
        }
    };

    // prologue: stage tile 0, prefetch adj window 0
    STAGE(0, jb0);
    LOADAV(0);
    __syncthreads();   // drains vmcnt(0): tile 0 + window 0 resident

    auto ITER = [&](int it, int cur) {
        // ---- 1) pack window `it`'s mask (frees pv), then issue next tile's
        //         DMA + next adj window (full iteration of latency slack)
        unsigned mcur = PACK();
        if (it + 1 < NIT) {
            STAGE(cur ^ 1, jb0 + it + 1);
            LOADAV(it + 1);
        }

        const _Float16* kb = &KV[cur][0];
        const _Float16* vb = &KV[cur][8192];

        // ---- 2) S^T = K Q^T : j = c*32 + 8*quad + 4*ntj + r, i = lo16 ----
        floatx4 S[2][2];   // [c][ntj]
#pragma unroll
        for (int c = 0; c < 2; c++)
#pragma unroll
            for (int ntj = 0; ntj < 2; ntj++) {
                S[c][ntj] = (floatx4){0.f, 0.f, 0.f, 0.f};
#pragma unroll
                for (int kc = 0; kc < 4; kc++) {
                    half8 kf = *(const half8*)&kb[(((c * 2 + ntj) * 4 + kc) * 64 + lane) * 8];
                    S[c][ntj] = __builtin_amdgcn_mfma_f32_16x16x32_f16(kf, q[kc], S[c][ntj], 0, 0, 0);
                }
            }

        // ---- 3) online softmax (exp2 domain), in-place lrelu, deferred
        //         rescale, bitmask test ----
        float mx = -1e12f;
#pragma unroll
        for (int c = 0; c < 2; c++)
#pragma unroll
            for (int ntj = 0; ntj < 2; ntj++)
#pragma unroll
                for (int r = 0; r < 4; r++) {
                    float e = S[c][ntj][r];
                    e = fmaxf(e, 0.2f * e);          // lrelu (scale-commutes)
                    S[c][ntj][r] = e;
                    mx = fmaxf(mx, e);
                }
        mx = fmaxf(mx, __shfl_xor(mx, 16));
        mx = fmaxf(mx, __shfl_xor(mx, 32));
        if (__any(mx > m_s + 5.75f)) {
            float mn = fmaxf(m_s, mx);
            float al = exp2_fast(m_s - mn);
            m_s = mn;
            l_s *= al;
#pragma unroll
            for (int nt = 0; nt < 8; nt++)
#pragma unroll
                for (int r = 0; r < 4; r++)
                    O[nt][r] *= al;
        }

        half8 pb[2];       // [c], element jj = ntj*4 + r
        float sum = 0.f;
#pragma unroll
        for (int c = 0; c < 2; c++)
#pragma unroll
            for (int ntj = 0; ntj < 2; ntj++)
#pragma unroll
                for (int r = 0; r < 4; r++) {
                    float e = S[c][ntj][r] - m_s;
                    bool bit = (mcur >> (c * 8 + ntj * 4 + r)) & 1u;
                    float p = bit ? exp2_fast(e) : 0.f;
                    sum += p;
                    pb[c][ntj * 4 + r] = (_Float16)p;
                }
        sum += __shfl_xor(sum, 16);
        sum += __shfl_xor(sum, 32);
        l_s += sum;

        // ---- 4) O^T += V^T P^T ----
#pragma unroll
        for (int c = 0; c < 2; c++)
#pragma unroll
            for (int nt = 0; nt < 8; nt++) {
                half8 vf = *(const half8*)&vb[((nt * 2 + c) * 64 + lane) * 8];
                O[nt] = __builtin_amdgcn_mfma_f32_16x16x32_f16(vf, pb[c], O[nt], 0, 0, 0);
            }

        // ---- 5) single barrier: drains this iter's DMA + adj prefetch ----
        __syncthreads();
    };

    for (int it2 = 0; it2 < NIT; it2 += 2) {
        ITER(it2,     0);
        ITER(it2 + 1, 1);
    }

    // epilogue: O^T[f][i] -> OpartT[js][f][i] (unnormalized) + (m,l)
#pragma unroll
    for (int nt = 0; nt < 8; nt++)
#pragma unroll
        for (int r = 0; r < 4; r++) {
            int f = nt * 16 + quad * 4 + r;
            OpartT[((size_t)js * FOUT + f) * N + irow] = O[nt][r];
        }
    if (quad == 0) {
        mpart[js * N + irow] = m_s;
        lpart[js * N + irow] = l_s;
    }
}

// ---------------------------------------------------------------------------
// Combine: f-major partials -> normalize -> ELU -> out[i][f].
// m is in log2 domain -> exp2 for the cross-partial weights.
// ---------------------------------------------------------------------------
template<int JS>
__global__ __launch_bounds__(256)
void combine_kernel(const float* __restrict__ OpartT,
                    const float* __restrict__ mpart,
                    const float* __restrict__ lpart,
                    float* __restrict__ out)
{
    int idx = blockIdx.x * 256 + threadIdx.x;   // 128 f x 2048 i-groups
    int f  = idx >> 11;
    int i4 = (idx & 2047) << 2;

    float4 M = {-3e38f, -3e38f, -3e38f, -3e38f};
    float4 m[JS];
#pragma unroll
    for (int s = 0; s < JS; s++) {
        m[s] = *(const float4*)&mpart[s * N + i4];
        M.x = fmaxf(M.x, m[s].x); M.y = fmaxf(M.y, m[s].y);
        M.z = fmaxf(M.z, m[s].z); M.w = fmaxf(M.w, m[s].w);
    }
    float4 L = {0.f, 0.f, 0.f, 0.f};
    float4 o = {0.f, 0.f, 0.f, 0.f};
#pragma unroll
    for (int s = 0; s < JS; s++) {
        float4 l = *(const float4*)&lpart[s * N + i4];
        float4 w;
        w.x = exp2_fast(m[s].x - M.x); w.y = exp2_fast(m[s].y - M.y);
        w.z = exp2_fast(m[s].z - M.z); w.w = exp2_fast(m[s].w - M.w);
        L.x += l.x * w.x; L.y += l.y * w.y;
        L.z += l.z * w.z; L.w += l.w * w.w;
        float4 v = *(const float4*)&OpartT[((size_t)s * FOUT + f) * N + i4];
        o.x += w.x * v.x; o.y += w.y * v.y;
        o.z += w.z * v.z; o.w += w.w * v.w;
    }
    float r0 = o.x / L.x, r1 = o.y / L.y, r2 = o.z / L.z, r3 = o.w / L.w;
    out[(size_t)(i4 + 0) * FOUT + f] = r0 > 0.f ? r0 : __expf(r0) - 1.f;
    out[(size_t)(i4 + 1) * FOUT + f] = r1 > 0.f ? r1 : __expf(r1) - 1.f;
    out[(size_t)(i4 + 2) * FOUT + f] = r2 > 0.f ? r2 : __expf(r2) - 1.f;
    out[(size_t)(i4 + 3) * FOUT + f] = r3 > 0.f ? r3 : __expf(r3) - 1.f;
}

// ---------------------------------------------------------------------------
extern "C" void kernel_launch(void* const* d_in, const int* in_sizes, int n_in,
                              void* d_out, int out_size, void* d_ws, size_t ws_size,
                              hipStream_t stream) {
    const float* inp = (const float*)d_in[0];
    const int*   adj = (const int*)d_in[1];
    const float* W0  = (const float*)d_in[2];
    const float* W1  = (const float*)d_in[3];
    const float* W2  = (const float*)d_in[4];
    float* out = (float*)d_out;

    constexpr int JS = 8;
    char* ws = (char*)d_ws;
    _Float16* H    = (_Float16*)(ws);                          // 2 MB
    _Float16* H2   = (_Float16*)(ws + (2u << 20));             // 2 MB
    _Float16* H3T  = (_Float16*)(ws + (4u << 20));             // 2 MB
    _Float16* Wf   = (_Float16*)(ws + (6u << 20));             // 192 KB
    _Float16* Kf   = (_Float16*)(ws + (7u << 20));             // 2 MB
    _Float16* Vf   = (_Float16*)(ws + (9u << 20));             // 2 MB
    float* OpartT  = (float*)(ws + (11u << 20));               // 32 MB
    float* mpart   = (float*)(ws + (43u << 20));               // 256 KB
    float* lpart   = (float*)(ws + (43u << 20) + (size_t)JS * N * sizeof(float));

    wprep_kernel<<<48, 256, 0, stream>>>(W0, W1, W2, Wf);
    gemm3_kernel<<<dim3(N / 64, 2, 3), 256, 0, stream>>>(inp, Wf, H, H2, H3T);
    repackKV_kernel<<<1024, 256, 0, stream>>>(H2, H3T, Kf, Vf);
    attn_kernel<JS><<<(N / 128) * JS, 512, 0, stream>>>(H, Kf, Vf, adj, OpartT, mpart, lpart);
    combine_kernel<JS><<<(FOUT * (N / 4)) / 256, 256, 0, stream>>>(OpartT, mpart, lpart, out);
}

// Round 10
// 412.922 us; speedup vs baseline: 1.1671x; 1.0257x over previous
//
#include <hip/hip_runtime.h>
#include <hip/hip_fp16.h>

#define N    8192
#define FIN  256
#define FOUT 128
#define BN   64

typedef _Float16 half8 __attribute__((ext_vector_type(8)));
typedef _Float16 half4v __attribute__((ext_vector_type(4)));
typedef float floatx4 __attribute__((ext_vector_type(4)));

// v_exp_f32 computes 2^x directly; __exp2f is not declared in these headers.
__device__ __forceinline__ float exp2_fast(float x) { return __builtin_amdgcn_exp2f(x); }

// Direct global->LDS DMA, 16 B per lane: LDS dest = wave-uniform base (HW adds
// lane*16); global src is per-lane.
__device__ __forceinline__ void gload_lds16(const void* g, void* l) {
    __builtin_amdgcn_global_load_lds(
        (const __attribute__((address_space(1))) void*)g,
        (__attribute__((address_space(3))) void*)l, 16, 0, 0);
}

// ---------------------------------------------------------------------------
// W-prep: frag-major fp16 W for coalesced MFMA B-loads.
// ---------------------------------------------------------------------------
__global__ __launch_bounds__(256)
void wprep_kernel(const float* __restrict__ W0,
                  const float* __restrict__ W1,
                  const float* __restrict__ W2,
                  _Float16* __restrict__ Wf)
{
    int idx  = blockIdx.x * 256 + threadIdx.x;   // 0..12287
    int lane = idx & 63;
    int frag = idx >> 6;
    int w    = frag >> 6;
    int f    = frag & 63;
    int nt   = f >> 3, kc = f & 7;
    int quad = lane >> 4, lo16 = lane & 15;
    const float* Wp = w == 0 ? W0 : (w == 1 ? W1 : W2);
    half8 v;
#pragma unroll
    for (int jj = 0; jj < 8; jj++)
        v[jj] = (_Float16)Wp[(size_t)(kc * 32 + quad * 8 + jj) * FOUT + nt * 16 + lo16];
    *(half8*)&Wf[(size_t)idx * 8] = v;
}

// ---------------------------------------------------------------------------
// H = fp16(log2e * inp@W), H2 = fp16(inp@W2), H3T = fp16((inp@W3)^T).
// (Proven body, unchanged.)
// ---------------------------------------------------------------------------
__global__ __launch_bounds__(256, 2)
void gemm3_kernel(const float* __restrict__ inp,
                  const _Float16* __restrict__ Wf,
                  _Float16* __restrict__ H,
                  _Float16* __restrict__ H2,
                  _Float16* __restrict__ H3T)
{
    const int which = blockIdx.z;
    const int c0    = blockIdx.y * 64;
    const _Float16* Wfw = Wf + (size_t)which * 64 * 64 * 8;
    const int r0 = blockIdx.x * 64;
    const int tid  = threadIdx.x;
    const int wave = tid >> 6;
    const int lane = tid & 63;
    const int lo16 = lane & 15;
    const int quad = lane >> 4;
    const int r = r0 + wave * 16 + lo16;

    half8 a[8];
#pragma unroll
    for (int kc = 0; kc < 8; kc++) {
        const float* p = &inp[(size_t)r * FIN + kc * 32 + quad * 8];
        float4 v0 = *(const float4*)p;
        float4 v1 = *(const float4*)(p + 4);
        a[kc][0] = (_Float16)v0.x; a[kc][1] = (_Float16)v0.y;
        a[kc][2] = (_Float16)v0.z; a[kc][3] = (_Float16)v0.w;
        a[kc][4] = (_Float16)v1.x; a[kc][5] = (_Float16)v1.y;
        a[kc][6] = (_Float16)v1.z; a[kc][7] = (_Float16)v1.w;
    }

    floatx4 acc[4];
#pragma unroll
    for (int i = 0; i < 4; i++) acc[i] = (floatx4){0.f, 0.f, 0.f, 0.f};

#pragma unroll
    for (int kc = 0; kc < 8; kc++)
#pragma unroll
        for (int nt = 0; nt < 4; nt++) {
            int ntg = (c0 >> 4) + nt;
            half8 b = *(const half8*)&Wfw[(((size_t)ntg * 8 + kc) * 64 + lane) * 8];
            acc[nt] = __builtin_amdgcn_mfma_f32_16x16x32_f16(a[kc], b, acc[nt], 0, 0, 0);
        }

    const int arow = wave * 16 + quad * 4;
    if (which < 2) {
        _Float16* outp = which == 0 ? H : H2;
        const float scale = which == 0 ? 1.44269504f : 1.0f;   // log2(e) folded into Q
#pragma unroll
        for (int nt = 0; nt < 4; nt++)
#pragma unroll
            for (int rr = 0; rr < 4; rr++)
                outp[(size_t)(r0 + arow + rr) * FOUT + c0 + nt * 16 + lo16] =
                    (_Float16)(acc[nt][rr] * scale);
    } else {
#pragma unroll
        for (int nt = 0; nt < 4; nt++) {
            half4v v;
#pragma unroll
            for (int rr = 0; rr < 4; rr++) v[rr] = (_Float16)acc[nt][rr];
            *(half4v*)&H3T[(size_t)(c0 + nt * 16 + lo16) * N + r0 + arow] = v;
        }
    }
}

// ---------------------------------------------------------------------------
// Fused repack: blocks [0,512) build Kf (sigma j-permutation baked in),
// blocks [512,1024) build Vf. (Proven, unchanged.)
// ---------------------------------------------------------------------------
__global__ __launch_bounds__(256)
void repackKV_kernel(const _Float16* __restrict__ H2,
                     const _Float16* __restrict__ H3T,
                     _Float16* __restrict__ Kf,
                     _Float16* __restrict__ Vf)
{
    if (blockIdx.x < 512) {
        int idx  = blockIdx.x * 256 + threadIdx.x;
        int lane = idx & 63;
        int frag = idx >> 6;
        int jb = frag >> 4, f = frag & 15;
        int c = f >> 3, ntj = (f >> 2) & 1, kc = f & 3;
        int quad = lane >> 4, lo16 = lane & 15;
        int srcrow = jb * 64 + c * 32 + (lo16 >> 2) * 8 + ntj * 4 + (lo16 & 3);
        half8 v = *(const half8*)&H2[(size_t)srcrow * FOUT + kc * 32 + quad * 8];
        *(half8*)&Kf[(size_t)idx * 8] = v;
    } else {
        int idx  = (blockIdx.x - 512) * 256 + threadIdx.x;
        int lane = idx & 63;
        int frag = idx >> 6;
        int jb = frag >> 4, f = frag & 15, nt = f >> 1, kc = f & 1;
        int quad = lane >> 4, lo16 = lane & 15;
        half8 v = *(const half8*)&H3T[(size_t)(nt * 16 + lo16) * N + jb * 64 + kc * 32 + quad * 8];
        *(half8*)&Vf[(size_t)idx * 8] = v;
    }
}

// ---------------------------------------------------------------------------
// Flash attention, R19: R18 base (512-thread / 8-wave blocks, gload_lds KV
// double-buffer, exp2 softmax, deferred rescale) with ONE delta: adj is read
// as FULLY CONTIGUOUS 1 KB whole-row spans (one dwordx4 per row covering a
// 4-window group) instead of 16-row-scattered int4s. Four ballots per row
// produce mask words whose natural bit layout (bit l = col 4l+r of word b_r)
// is consumed directly: bit(c,ntj,r) at iter p = bit (p*16+c*8+quad*2+ntj)
// of m[r]. Masks ping-pong in mA/mB (4 u64 each); rows for group g+1 load at
// the top of group-g iters (4 rows/iter) and ballot at the bottom -> full
// iteration of latency slack. Same total adj bytes; requests now 1 KB
// contiguous (channel-balanced) instead of 16x16B at 32 KB stride.
// ---------------------------------------------------------------------------
template<int JS>
__global__ __launch_bounds__(512, 2)
void attn_kernel(const _Float16* __restrict__ Hq,   // [N][128], log2e folded
                 const _Float16* __restrict__ Kf,   // permuted frag-major
                 const _Float16* __restrict__ Vf,   // frag-major
                 const int* __restrict__ adj,       // [N][N]
                 float* __restrict__ OpartT,        // [JS][FOUT][N]
                 float* __restrict__ mpart,         // [JS][N]  (log2 domain)
                 float* __restrict__ lpart)         // [JS][N]
{
    __shared__ __align__(16) _Float16 KV[2][16384];   // [buf][16 K frags | 16 V frags]

    const int tid  = threadIdx.x;        // 0..511
    const int wave = tid >> 6;           // 0..7
    const int lane = tid & 63;
    const int lo16 = lane & 15;
    const int quad = lane >> 4;
    const int qsh  = quad * 2;           // mask shift component
    const int bid  = blockIdx.x;
    const int js   = bid & (JS - 1);     // XCD affinity
    const int ib   = bid / JS;
    const int iw   = ib * 128 + wave * 16;   // this wave's 16-row slice
    const int irow = iw + lo16;              // this lane's i-row
    const int jbeg = js * (N / JS);
    constexpr int NIT = 16;              // (N/JS)/BN
    const int jb0  = jbeg >> 6;

    // Q fragments (B-operand) for this lane's row
    half8 q[4];
#pragma unroll
    for (int kc = 0; kc < 4; kc++)
        q[kc] = *(const half8*)&Hq[(size_t)irow * FOUT + kc * 32 + quad * 8];

    floatx4 O[8];
#pragma unroll
    for (int nt = 0; nt < 8; nt++) O[nt] = (floatx4){0.f, 0.f, 0.f, 0.f};
    float m_s = -1e12f, l_s = 0.f;

    // whole-row adj reads: wave reads row (iw+x), 1 KB span (4 windows),
    // lane l -> cols g*256 + 4l .. 4l+3. Perfectly coalesced dwordx4.
    const int* arow_base = adj + (size_t)iw * N + jbeg + lane * 4;

    unsigned long long mA[4], mB[4];     // mask ping-pong: word r, bit l = col 4l+r

    auto STAGE = [&](int nxt, int jbn) {
        const _Float16* gk = Kf + (size_t)jbn * 8192;
        const _Float16* gv = Vf + (size_t)jbn * 8192;
#pragma unroll
        for (int r = 0; r < 2; r++) {
            int goff = (r * 512 + tid) * 8;
            int loff = (r * 512 + wave * 64) * 8;            // wave-uniform base
            gload_lds16(gk + goff, &KV[nxt][loff]);
            gload_lds16(gv + goff, &KV[nxt][8192 + loff]);
        }
    };

    // ballot 4 rows' loaded values into mask words (select by lo16==row)
    auto BALLOT4 = [&](unsigned long long (&mn)[4], int p,
                       const int4& a0, const int4& a1, const int4& a2, const int4& a3) {
#pragma unroll
        for (int qq = 0; qq < 4; qq++) {
            const int4& a = (qq == 0) ? a0 : (qq == 1) ? a1 : (qq == 2) ? a2 : a3;
            unsigned long long b0 = __ballot(a.x != 0);
            unsigned long long b1 = __ballot(a.y != 0);
            unsigned long long b2 = __ballot(a.z != 0);
            unsigned long long b3 = __ballot(a.w != 0);
            bool sel = (lo16 == p * 4 + qq);
            mn[0] = sel ? b0 : mn[0];
            mn[1] = sel ? b1 : mn[1];
            mn[2] = sel ? b2 : mn[2];
            mn[3] = sel ? b3 : mn[3];
        }
    };

    // prologue: stage KV tile 0; build group-0 masks (16 contiguous row reads)
    STAGE(0, jb0);
#pragma unroll
    for (int p = 0; p < 4; p++) {
        const int* rb = arow_base;                       // group 0 base
        int4 a0 = *(const int4*)(rb + (size_t)(p * 4 + 0) * N);
        int4 a1 = *(const int4*)(rb + (size_t)(p * 4 + 1) * N);
        int4 a2 = *(const int4*)(rb + (size_t)(p * 4 + 2) * N);
        int4 a3 = *(const int4*)(rb + (size_t)(p * 4 + 3) * N);
        BALLOT4(mA, p, a0, a1, a2, a3);
    }
    __syncthreads();   // drains vmcnt(0): tile 0 resident

    auto ITER = [&](int it, int p, unsigned long long (&mc)[4],
                    unsigned long long (&mn)[4], bool buildNext, int gnext) {
        const int cur = it & 1;

        // ---- 1) issue next-group row loads (4 contiguous 1 KB reads) ----
        int4 a0, a1, a2, a3;
        if (buildNext) {
            const int* rb = arow_base + gnext * 256;
            a0 = *(const int4*)(rb + (size_t)(p * 4 + 0) * N);
            a1 = *(const int4*)(rb + (size_t)(p * 4 + 1) * N);
            a2 = *(const int4*)(rb + (size_t)(p * 4 + 2) * N);
            a3 = *(const int4*)(rb + (size_t)(p * 4 + 3) * N);
        }
        // ---- 2) stage next KV tile ----
        if (it + 1 < NIT) STAGE(cur ^ 1, jb0 + it + 1);

        const _Float16* kb = &KV[cur][0];
        const _Float16* vb = &KV[cur][8192];

        // ---- 3) S^T = K Q^T : j = c*32 + 8*quad + 4*ntj + r, i = lo16 ----
        floatx4 S[2][2];   // [c][ntj]
#pragma unroll
        for (int c = 0; c < 2; c++)
#pragma unroll
            for (int ntj = 0; ntj < 2; ntj++) {
                S[c][ntj] = (floatx4){0.f, 0.f, 0.f, 0.f};
#pragma unroll
                for (int kc = 0; kc < 4; kc++) {
                    half8 kf = *(const half8*)&kb[(((c * 2 + ntj) * 4 + kc) * 64 + lane) * 8];
                    S[c][ntj] = __builtin_amdgcn_mfma_f32_16x16x32_f16(kf, q[kc], S[c][ntj], 0, 0, 0);
                }
            }

        // ---- 4) online softmax (exp2), in-place lrelu, deferred rescale ----
        float mx = -1e12f;
#pragma unroll
        for (int c = 0; c < 2; c++)
#pragma unroll
            for (int ntj = 0; ntj < 2; ntj++)
#pragma unroll
                for (int r = 0; r < 4; r++) {
                    float e = S[c][ntj][r];
                    e = fmaxf(e, 0.2f * e);          // lrelu (scale-commutes)
                    S[c][ntj][r] = e;
                    mx = fmaxf(mx, e);
                }
        mx = fmaxf(mx, __shfl_xor(mx, 16));
        mx = fmaxf(mx, __shfl_xor(mx, 32));
        if (__any(mx > m_s + 5.75f)) {
            float mn2 = fmaxf(m_s, mx);
            float al = exp2_fast(m_s - mn2);
            m_s = mn2;
            l_s *= al;
#pragma unroll
            for (int nt = 0; nt < 8; nt++)
#pragma unroll
                for (int r = 0; r < 4; r++)
                    O[nt][r] *= al;
        }

        half8 pb[2];       // [c], element jj = ntj*4 + r
        float sum = 0.f;
#pragma unroll
        for (int c = 0; c < 2; c++)
#pragma unroll
            for (int ntj = 0; ntj < 2; ntj++)
#pragma unroll
                for (int r = 0; r < 4; r++) {
                    float e = S[c][ntj][r] - m_s;
                    // bit l = p*16 + c*8 + quad*2 + ntj of word mc[r]
                    bool bit = (mc[r] >> (p * 16 + c * 8 + ntj + qsh)) & 1ull;
                    float pp = bit ? exp2_fast(e) : 0.f;
                    sum += pp;
                    pb[c][ntj * 4 + r] = (_Float16)pp;
                }
        sum += __shfl_xor(sum, 16);
        sum += __shfl_xor(sum, 32);
        l_s += sum;

        // ---- 5) O^T += V^T P^T ----
#pragma unroll
        for (int c = 0; c < 2; c++)
#pragma unroll
            for (int nt = 0; nt < 8; nt++) {
                half8 vf = *(const half8*)&vb[((nt * 2 + c) * 64 + lane) * 8];
                O[nt] = __builtin_amdgcn_mfma_f32_16x16x32_f16(vf, pb[c], O[nt], 0, 0, 0);
            }

        // ---- 6) ballot the row loads issued at step 1 (full iter of slack)
        if (buildNext) BALLOT4(mn, p, a0, a1, a2, a3);

        // ---- 7) single barrier: drains this iter's DMA + row loads ----
        __syncthreads();
    };

    // main loop: 4 groups x 4 windows; masks ping-pong mA <-> mB
#pragma unroll
    for (int g = 0; g < 4; g++) {
#pragma unroll
        for (int p = 0; p < 4; p++) {
            int it = g * 4 + p;
            if (g & 1) ITER(it, p, mB, mA, g < 3, g + 1);
            else       ITER(it, p, mA, mB, g < 3, g + 1);
        }
    }

    // epilogue: O^T[f][i] -> OpartT[js][f][i] (unnormalized) + (m,l)
#pragma unroll
    for (int nt = 0; nt < 8; nt++)
#pragma unroll
        for (int r = 0; r < 4; r++) {
            int f = nt * 16 + quad * 4 + r;
            OpartT[((size_t)js * FOUT + f) * N + irow] = O[nt][r];
        }
    if (quad == 0) {
        mpart[js * N + irow] = m_s;
        lpart[js * N + irow] = l_s;
    }
}

// ---------------------------------------------------------------------------
// Combine: f-major partials -> normalize -> ELU -> out[i][f].
// m is in log2 domain -> exp2 for the cross-partial weights.
// ---------------------------------------------------------------------------
template<int JS>
__global__ __launch_bounds__(256)
void combine_kernel(const float* __restrict__ OpartT,
                    const float* __restrict__ mpart,
                    const float* __restrict__ lpart,
                    float* __restrict__ out)
{
    int idx = blockIdx.x * 256 + threadIdx.x;   // 128 f x 2048 i-groups
    int f  = idx >> 11;
    int i4 = (idx & 2047) << 2;

    float4 M = {-3e38f, -3e38f, -3e38f, -3e38f};
    float4 m[JS];
#pragma unroll
    for (int s = 0; s < JS; s++) {
        m[s] = *(const float4*)&mpart[s * N + i4];
        M.x = fmaxf(M.x, m[s].x); M.y = fmaxf(M.y, m[s].y);
        M.z = fmaxf(M.z, m[s].z); M.w = fmaxf(M.w, m[s].w);
    }
    float4 L = {0.f, 0.f, 0.f, 0.f};
    float4 o = {0.f, 0.f, 0.f, 0.f};
#pragma unroll
    for (int s = 0; s < JS; s++) {
        float4 l = *(const float4*)&lpart[s * N + i4];
        float4 w;
        w.x = exp2_fast(m[s].x - M.x); w.y = exp2_fast(m[s].y - M.y);
        w.z = exp2_fast(m[s].z - M.z); w.w = exp2_fast(m[s].w - M.w);
        L.x += l.x * w.x; L.y += l.y * w.y;
        L.z += l.z * w.z; L.w += l.w * w.w;
        float4 v = *(const float4*)&OpartT[((size_t)s * FOUT + f) * N + i4];
        o.x += w.x * v.x; o.y += w.y * v.y;
        o.z += w.z * v.z; o.w += w.w * v.w;
    }
    float r0 = o.x / L.x, r1 = o.y / L.y, r2 = o.z / L.z, r3 = o.w / L.w;
    out[(size_t)(i4 + 0) * FOUT + f] = r0 > 0.f ? r0 : __expf(r0) - 1.f;
    out[(size_t)(i4 + 1) * FOUT + f] = r1 > 0.f ? r1 : __expf(r1) - 1.f;
    out[(size_t)(i4 + 2) * FOUT + f] = r2 > 0.f ? r2 : __expf(r2) - 1.f;
    out[(size_t)(i4 + 3) * FOUT + f] = r3 > 0.f ? r3 : __expf(r3) - 1.f;
}

// ---------------------------------------------------------------------------
extern "C" void kernel_launch(void* const* d_in, const int* in_sizes, int n_in,
                              void* d_out, int out_size, void* d_ws, size_t ws_size,
                              hipStream_t stream) {
    const float* inp = (const float*)d_in[0];
    const int*   adj = (const int*)d_in[1];
    const float* W0  = (const float*)d_in[2];
    const float* W1  = (const float*)d_in[3];
    const float* W2  = (const float*)d_in[4];
    float* out = (float*)d_out;

    constexpr int JS = 8;
    char* ws = (char*)d_ws;
    _Float16* H    = (_Float16*)(ws);                          // 2 MB
    _Float16* H2   = (_Float16*)(ws + (2u << 20));             // 2 MB
    _Float16* H3T  = (_Float16*)(ws + (4u << 20));             // 2 MB
    _Float16* Wf   = (_Float16*)(ws + (6u << 20));             // 192 KB
    _Float16* Kf   = (_Float16*)(ws + (7u << 20));             // 2 MB
    _Float16* Vf   = (_Float16*)(ws + (9u << 20));             // 2 MB
    float* OpartT  = (float*)(ws + (11u << 20));               // 32 MB
    float* mpart   = (float*)(ws + (43u << 20));               // 256 KB
    float* lpart   = (float*)(ws + (43u << 20) + (size_t)JS * N * sizeof(float));

    wprep_kernel<<<48, 256, 0, stream>>>(W0, W1, W2, Wf);
    gemm3_kernel<<<dim3(N / 64, 2, 3), 256, 0, stream>>>(inp, Wf, H, H2, H3T);
    repackKV_kernel<<<1024, 256, 0, stream>>>(H2, H3T, Kf, Vf);
    attn_kernel<JS><<<(N / 128) * JS, 512, 0, stream>>>(H, Kf, Vf, adj, OpartT, mpart, lpart);
    combine_kernel<JS><<<(FOUT * (N / 4)) / 256, 256, 0, stream>>>(OpartT, mpart, lpart, out);
}